// Round 1
// baseline (3782.888 us; speedup 1.0000x reference)
//
#include <hip/hip_runtime.h>
#include <math.h>

// ===== problem constants =====
#define NB   4
#define NS   1024
#define ND   1024
#define NH   16
#define NTOK 4096     // NB*NS
#define NFE  1024

// ===== workspace layout (float offsets) =====
static constexpr size_t OFF_X    = 0;                       // 4096*1024  x ; later aliased as o_proj
static constexpr size_t OFF_QA   = OFF_X   + 4194304;       // 4096*512
static constexpr size_t OFF_QB   = OFF_QA  + 2097152;       // 4096*1536
static constexpr size_t OFF_KVP  = OFF_QB  + 6291456;       // 4096*288
static constexpr size_t OFF_KVN  = OFF_KVP + 1179648;       // 4096*256
static constexpr size_t OFF_H    = OFF_KVN + 1048576;       // 4096*1024
static constexpr size_t OFF_Y    = OFF_H   + 4194304;       // 4096*1024
static constexpr size_t OFF_TKW  = OFF_Y   + 4194304;       // 8192
static constexpr size_t OFF_EW   = OFF_TKW + 8192;          // 9216
static constexpr size_t OFF_INT  = OFF_EW  + 9216;          // int region below
static constexpr size_t IOFF_TKE  = 0;                      // 8192 ints
static constexpr size_t IOFF_ETOK = 8192;                   // 9216 ints
static constexpr size_t IOFF_CNT  = 17408;                  // 16 cnt | 16 cnt2 | 16 base | 16 pcnt
static constexpr size_t WS_FLOATS = OFF_INT + 17472;
// aliases (lifetimes don't overlap):
static constexpr size_t OFF_ACT   = OFF_QA;   // 9216*1024 spans QA..KVP region (ends < OFF_KVN)
static constexpr size_t OFF_OPROJ = OFF_X;    // x is dead once attention runs

// ===================== RMSNorm =====================
template<int PER>
__global__ __launch_bounds__(256) void rmsnorm_kernel(
    const float* in, int istr, const float* w, float* out, int ostr)
{
  int row = blockIdx.x, t = threadIdx.x;
  const float* ip = in + (size_t)row * istr;
  float v[PER];
  float ss = 0.f;
#pragma unroll
  for (int i = 0; i < PER; i++) { v[i] = ip[t + i*256]; ss += v[i]*v[i]; }
#pragma unroll
  for (int k = 1; k < 64; k <<= 1) ss += __shfl_xor(ss, k);
  __shared__ float red[4];
  if ((t & 63) == 0) red[t >> 6] = ss;
  __syncthreads();
  float tot = red[0] + red[1] + red[2] + red[3];
  float inv = rsqrtf(tot * (1.f / (PER * 256)) + 1e-6f);
  float* op = out + (size_t)row * ostr;
#pragma unroll
  for (int i = 0; i < PER; i++) op[t + i*256] = v[i] * inv * w[t + i*256];
}

// ===================== generic f32 GEMM: C = A @ W^T (+bias)(+resid) =====================
// tiles 64x64, BK=16, 256 threads, 4x4 micro-tile. M multiple of 64, K multiple of 16, N guarded.
__global__ __launch_bounds__(256) void gemm_nt(
    const float* __restrict__ A, int lda,
    const float* __restrict__ W, int ldw,
    const float* __restrict__ bias,
    const float* __restrict__ resid,
    float* __restrict__ C, int ldc,
    float* __restrict__ C2,
    int N, int K)
{
  __shared__ __align__(16) float As[16][68];
  __shared__ __align__(16) float Ws[16][68];
  int t = threadIdx.x;
  int m0 = blockIdx.y * 64, n0 = blockIdx.x * 64;
  int lm = t >> 2, lk = (t & 3) << 2;
  int tx = t & 15, ty = t >> 4;
  const float* ap = A + (size_t)(m0 + lm) * lda + lk;
  bool wok = (n0 + lm) < N;
  const float* wp = wok ? (W + (size_t)(n0 + lm) * ldw + lk) : nullptr;
  float acc[4][4] = {};
  for (int k0 = 0; k0 < K; k0 += 16) {
    float4 av = *(const float4*)(ap + k0);
    float4 wv = wok ? *(const float4*)(wp + k0) : make_float4(0.f, 0.f, 0.f, 0.f);
    As[lk+0][lm] = av.x; As[lk+1][lm] = av.y; As[lk+2][lm] = av.z; As[lk+3][lm] = av.w;
    Ws[lk+0][lm] = wv.x; Ws[lk+1][lm] = wv.y; Ws[lk+2][lm] = wv.z; Ws[lk+3][lm] = wv.w;
    __syncthreads();
#pragma unroll
    for (int k = 0; k < 16; k++) {
      float a[4], b[4];
      *(float4*)a = *(const float4*)&As[k][ty << 2];
      *(float4*)b = *(const float4*)&Ws[k][tx << 2];
#pragma unroll
      for (int i = 0; i < 4; i++)
#pragma unroll
        for (int j = 0; j < 4; j++) acc[i][j] += a[i] * b[j];
    }
    __syncthreads();
  }
#pragma unroll
  for (int i = 0; i < 4; i++) {
    int m = m0 + (ty << 2) + i;
#pragma unroll
    for (int j = 0; j < 4; j++) {
      int n = n0 + (tx << 2) + j;
      if (n < N) {
        float v = acc[i][j];
        if (bias)  v += bias[n];
        size_t off = (size_t)m * ldc + n;
        if (resid) v += resid[off];
        C[off] = v;
        if (C2) C2[off] = v;
      }
    }
  }
}

// ===================== RoPE =====================
__global__ __launch_bounds__(256) void rope_q_kernel(float* qbuf)
{
  int id = blockIdx.x * 256 + threadIdx.x;     // NTOK*NH*16
  int d = id & 15;
  int h = (id >> 4) & 15;
  int sr = id >> 8;                            // 0..4095
  int s = sr & (NS - 1);
  float inv = __expf(-(float)(2 * d) * (9.210340371976184f / 32.f)); // 10000^(-2d/32)
  float fr = (float)s * inv;
  float sn, cs; sincosf(fr, &sn, &cs);
  float* p = qbuf + (size_t)sr * 1536 + h * 96 + 64;
  float x1 = p[d], x2 = p[d + 16];
  p[d]      = x1 * cs - x2 * sn;
  p[d + 16] = x2 * cs + x1 * sn;
}

__global__ __launch_bounds__(256) void rope_k_kernel(float* kvp)
{
  int id = blockIdx.x * 256 + threadIdx.x;     // NTOK*16
  int d = id & 15;
  int sr = id >> 4;
  int s = sr & (NS - 1);
  float inv = __expf(-(float)(2 * d) * (9.210340371976184f / 32.f));
  float fr = (float)s * inv;
  float sn, cs; sincosf(fr, &sn, &cs);
  float* p = kvp + (size_t)sr * 288 + 256;
  float x1 = p[d], x2 = p[d + 16];
  p[d]      = x1 * cs - x2 * sn;
  p[d + 16] = x2 * cs + x1 * sn;
}

// ===================== MLA flash attention =====================
// grid (S/64, H, B), 256 threads, dynamic LDS.
// Per block: fuse q_abs = q_nope @ wkv_b[h,:64,:], flash over K-tiles of 32 shared
// 288-dim keys (kv||pe), epilogue fuses o @ wkv_b[h,64:,:]^T -> o_proj (B*S, H*64).
#define QSTR 292
#define KSTR 292
#define SSTR 36

__global__ __launch_bounds__(256) void attn_kernel(
    const float* __restrict__ qbuf,  // (NTOK, H*96)
    const float* __restrict__ kvn,   // (NTOK, 256)
    const float* __restrict__ kvp,   // (NTOK, 288), pe at +256
    const float* __restrict__ wkvb,  // (H*128, 256)
    float* __restrict__ oproj)       // (NTOK, H*64)
{
  extern __shared__ float smem[];
  float* qt   = smem;                 // [64][QSTR] : q_abs(256)|q_pe(32), pre-scaled
  float* kvt  = qt  + 64 * QSTR;      // [32][KSTR]
  float* sc   = kvt + 32 * KSTR;      // [64][SSTR]
  float* mrow = sc  + 64 * SSTR;      // [64]
  float* lrow = mrow + 64;
  float* arow = lrow + 64;
  int qb = blockIdx.x, h = blockIdx.y, b = blockIdx.z;
  int t = threadIdx.x;
  int row0 = b * NS + qb * 64;
  const float scale = 0.10206207261596577f;  // 1/sqrt(96)
  // phase 0a: load q_nope (into kvt-as-scratch) and q_pe (into qt cols 256..287), scaled
  float* qn = kvt;                    // [64][68] scratch
  for (int idx = t; idx < 64 * 96; idx += 256) {
    int r = idx / 96, c = idx % 96;
    float v = qbuf[(size_t)(row0 + r) * 1536 + h * 96 + c] * scale;
    if (c < 64) qn[r * 68 + c] = v;
    else        qt[r * QSTR + 256 + (c - 64)] = v;
  }
  __syncthreads();
  int cx = t & 63, ry = t >> 6;       // o mapping: cols 4cx.., rows 16ry..
  // phase 0b: qt[:, 0:256] = q_nope @ wkv_b[h, 0:64, :]
  {
    float a[16][4];
#pragma unroll
    for (int r = 0; r < 16; r++) { a[r][0]=0.f; a[r][1]=0.f; a[r][2]=0.f; a[r][3]=0.f; }
    const float* wb = wkvb + (size_t)h * 128 * 256 + cx * 4;
    for (int k = 0; k < 64; k++) {
      float4 wv = *(const float4*)(wb + (size_t)k * 256);
#pragma unroll
      for (int r = 0; r < 16; r++) {
        float qv = qn[(ry * 16 + r) * 68 + k];
        a[r][0] += qv * wv.x; a[r][1] += qv * wv.y; a[r][2] += qv * wv.z; a[r][3] += qv * wv.w;
      }
    }
    __syncthreads();  // all qn reads done before flash loop clobbers kvt
#pragma unroll
    for (int r = 0; r < 16; r++)
      *(float4*)&qt[(ry * 16 + r) * QSTR + cx * 4] =
        make_float4(a[r][0], a[r][1], a[r][2], a[r][3]);
  }
  if (t < 64) { mrow[t] = -INFINITY; lrow[t] = 0.f; }
  float o[16][4];
#pragma unroll
  for (int r = 0; r < 16; r++) { o[r][0]=0.f; o[r][1]=0.f; o[r][2]=0.f; o[r][3]=0.f; }
  __syncthreads();
  int nkb = 2 * qb + 2;
  for (int kb = 0; kb < nkb; kb++) {
    int key0 = kb * 32;
    for (int idx = t; idx < 32 * 288; idx += 256) {
      int r = idx / 288, c = idx % 288;
      int tk = b * NS + key0 + r;
      float v = (c < 256) ? kvn[(size_t)tk * 256 + c] : kvp[(size_t)tk * 288 + c];
      kvt[r * KSTR + c] = v;
    }
    __syncthreads();
    // scores: thread -> rows r0..r0+1, keys j0..j0+3
    {
      int kx = t & 7, ryy = t >> 3;
      int r0 = ryy * 2, j0 = kx * 4;
      float s00=0,s01=0,s02=0,s03=0,s10=0,s11=0,s12=0,s13=0;
      for (int d = 0; d < 288; d += 4) {
        float4 q0 = *(const float4*)&qt[r0 * QSTR + d];
        float4 q1 = *(const float4*)&qt[(r0 + 1) * QSTR + d];
        float4 k0 = *(const float4*)&kvt[(j0 + 0) * KSTR + d];
        float4 k1 = *(const float4*)&kvt[(j0 + 1) * KSTR + d];
        float4 k2 = *(const float4*)&kvt[(j0 + 2) * KSTR + d];
        float4 k3 = *(const float4*)&kvt[(j0 + 3) * KSTR + d];
        s00 += q0.x*k0.x + q0.y*k0.y + q0.z*k0.z + q0.w*k0.w;
        s01 += q0.x*k1.x + q0.y*k1.y + q0.z*k1.z + q0.w*k1.w;
        s02 += q0.x*k2.x + q0.y*k2.y + q0.z*k2.z + q0.w*k2.w;
        s03 += q0.x*k3.x + q0.y*k3.y + q0.z*k3.z + q0.w*k3.w;
        s10 += q1.x*k0.x + q1.y*k0.y + q1.z*k0.z + q1.w*k0.w;
        s11 += q1.x*k1.x + q1.y*k1.y + q1.z*k1.z + q1.w*k1.w;
        s12 += q1.x*k2.x + q1.y*k2.y + q1.z*k2.z + q1.w*k2.w;
        s13 += q1.x*k3.x + q1.y*k3.y + q1.z*k3.z + q1.w*k3.w;
      }
      int g0 = qb * 64 + r0, g1 = g0 + 1;  // global query rows
      sc[r0*SSTR + j0+0]     = (key0+j0+0 <= g0) ? s00 : -1e30f;
      sc[r0*SSTR + j0+1]     = (key0+j0+1 <= g0) ? s01 : -1e30f;
      sc[r0*SSTR + j0+2]     = (key0+j0+2 <= g0) ? s02 : -1e30f;
      sc[r0*SSTR + j0+3]     = (key0+j0+3 <= g0) ? s03 : -1e30f;
      sc[(r0+1)*SSTR + j0+0] = (key0+j0+0 <= g1) ? s10 : -1e30f;
      sc[(r0+1)*SSTR + j0+1] = (key0+j0+1 <= g1) ? s11 : -1e30f;
      sc[(r0+1)*SSTR + j0+2] = (key0+j0+2 <= g1) ? s12 : -1e30f;
      sc[(r0+1)*SSTR + j0+3] = (key0+j0+3 <= g1) ? s13 : -1e30f;
    }
    __syncthreads();
    // online softmax per row
    if (t < 64) {
      float mx = -1e30f;
#pragma unroll
      for (int j = 0; j < 32; j++) mx = fmaxf(mx, sc[t * SSTR + j]);
      float mold = mrow[t];
      float mnew = fmaxf(mold, mx);
      float al = __expf(mold - mnew);
      float sum = 0.f;
#pragma unroll
      for (int j = 0; j < 32; j++) {
        float p = __expf(sc[t * SSTR + j] - mnew);
        sc[t * SSTR + j] = p; sum += p;
      }
      lrow[t] = lrow[t] * al + sum;
      mrow[t] = mnew;
      arow[t] = al;
    }
    __syncthreads();
    // o = o*alpha + P @ kv
    {
#pragma unroll
      for (int r = 0; r < 16; r++) {
        float al = arow[ry * 16 + r];
        o[r][0] *= al; o[r][1] *= al; o[r][2] *= al; o[r][3] *= al;
      }
      for (int j = 0; j < 32; j += 4) {
        float4 v0 = *(const float4*)&kvt[(j + 0) * KSTR + cx * 4];
        float4 v1 = *(const float4*)&kvt[(j + 1) * KSTR + cx * 4];
        float4 v2 = *(const float4*)&kvt[(j + 2) * KSTR + cx * 4];
        float4 v3 = *(const float4*)&kvt[(j + 3) * KSTR + cx * 4];
#pragma unroll
        for (int r = 0; r < 16; r++) {
          float4 p = *(const float4*)&sc[(ry * 16 + r) * SSTR + j];
          o[r][0] += p.x*v0.x + p.y*v1.x + p.z*v2.x + p.w*v3.x;
          o[r][1] += p.x*v0.y + p.y*v1.y + p.z*v2.y + p.w*v3.y;
          o[r][2] += p.x*v0.z + p.y*v1.z + p.z*v2.z + p.w*v3.z;
          o[r][3] += p.x*v0.w + p.y*v1.w + p.z*v2.w + p.w*v3.w;
        }
      }
    }
    __syncthreads();
  }
  // normalize, stash o into qt (reuse)
#pragma unroll
  for (int r = 0; r < 16; r++) {
    float inv = 1.f / lrow[ry * 16 + r];
    *(float4*)&qt[(ry * 16 + r) * QSTR + cx * 4] =
      make_float4(o[r][0]*inv, o[r][1]*inv, o[r][2]*inv, o[r][3]*inv);
  }
  __syncthreads();
  // epilogue: out[r][d] = sum_c o[r][c] * wkv_b[h,64+d,c]
  {
    int dx = t & 15, ty2 = t >> 4;
    float pr[4][4];
#pragma unroll
    for (int i = 0; i < 4; i++) { pr[i][0]=0.f; pr[i][1]=0.f; pr[i][2]=0.f; pr[i][3]=0.f; }
    const float* wb = wkvb + (size_t)(h * 128 + 64) * 256;
    for (int c = 0; c < 256; c += 4) {
      float4 w0 = *(const float4*)(wb + (size_t)(dx * 4 + 0) * 256 + c);
      float4 w1 = *(const float4*)(wb + (size_t)(dx * 4 + 1) * 256 + c);
      float4 w2 = *(const float4*)(wb + (size_t)(dx * 4 + 2) * 256 + c);
      float4 w3 = *(const float4*)(wb + (size_t)(dx * 4 + 3) * 256 + c);
#pragma unroll
      for (int i = 0; i < 4; i++) {
        float4 ov = *(const float4*)&qt[(ty2 * 4 + i) * QSTR + c];
        pr[i][0] += ov.x*w0.x + ov.y*w0.y + ov.z*w0.z + ov.w*w0.w;
        pr[i][1] += ov.x*w1.x + ov.y*w1.y + ov.z*w1.z + ov.w*w1.w;
        pr[i][2] += ov.x*w2.x + ov.y*w2.y + ov.z*w2.z + ov.w*w2.w;
        pr[i][3] += ov.x*w3.x + ov.y*w3.y + ov.z*w3.z + ov.w*w3.w;
      }
    }
#pragma unroll
    for (int i = 0; i < 4; i++)
#pragma unroll
      for (int j = 0; j < 4; j++)
        oproj[(size_t)(row0 + ty2 * 4 + i) * 1024 + h * 64 + dx * 4 + j] = pr[i][j];
  }
}

// ===================== gate logits =====================
__global__ __launch_bounds__(256) void gate_kernel(
    const float* __restrict__ Y, const float* __restrict__ gw,
    const float* __restrict__ gb, float* __restrict__ logits)
{
  __shared__ __align__(16) float ly[1024];
  int tok = blockIdx.x, t = threadIdx.x;
  *(float4*)&ly[t * 4] = *(const float4*)(Y + (size_t)tok * ND + t * 4);
  __syncthreads();
  int e = t >> 5, lane = t & 31;
  const float* w = gw + (size_t)e * ND;
  float ss = 0.f;
  for (int d = lane; d < ND; d += 32) ss += ly[d] * w[d];
#pragma unroll
  for (int k = 16; k >= 1; k >>= 1) ss += __shfl_xor(ss, k);
  if (lane == 0) logits[(size_t)tok * 8 + e] = ss + gb[e];
}

// ===================== top-2 gating + counts =====================
__global__ __launch_bounds__(256) void topk_kernel(
    const float* __restrict__ logits, int* __restrict__ tke,
    float* __restrict__ tkw, int* __restrict__ cnt)
{
  int tok = blockIdx.x * 256 + threadIdx.x;
  if (tok >= NTOK) return;
  float l[8];
#pragma unroll
  for (int e2 = 0; e2 < 8; e2++) l[e2] = logits[(size_t)tok * 8 + e2];
  float v0 = l[0]; int e0 = 0;
#pragma unroll
  for (int e2 = 1; e2 < 8; e2++) if (l[e2] > v0) { v0 = l[e2]; e0 = e2; }
  float v1 = -INFINITY; int e1 = 0;
#pragma unroll
  for (int e2 = 0; e2 < 8; e2++) if (e2 != e0 && l[e2] > v1) { v1 = l[e2]; e1 = e2; }
  float x = __expf(v1 - v0);
  float w0 = 1.f / (1.f + x);
  tke[tok * 2]     = e0; tke[tok * 2 + 1] = e1;
  tkw[tok * 2]     = w0; tkw[tok * 2 + 1] = 1.f - w0;
  atomicAdd(&cnt[e0], 1);
  atomicAdd(&cnt[8 + e1], 1);
}

__global__ void offsets_kernel(const int* cnt, int* base, int* pcnt)
{
  if (threadIdx.x == 0 && blockIdx.x == 0) {
    int cum = 0;
    for (int s2 = 0; s2 < 16; s2++) {
      int p = (cnt[s2] + 63) & ~63;
      base[s2] = cum; pcnt[s2] = p; cum += p;
    }
  }
}

__global__ __launch_bounds__(256) void scatter_kernel(
    const int* __restrict__ tke, const float* __restrict__ tkw,
    const int* __restrict__ base, int* cnt2,
    int* __restrict__ etok, float* __restrict__ ew)
{
  int tok = blockIdx.x * 256 + threadIdx.x;
  if (tok >= NTOK) return;
#pragma unroll
  for (int k = 0; k < 2; k++) {
    int e = tke[tok * 2 + k];
    int seg = k * 8 + e;
    int pos = atomicAdd(&cnt2[seg], 1);
    int row = base[seg] + pos;
    etok[row] = tok;
    ew[row] = tkw[tok * 2 + k];
  }
}

// ===================== MoE mlp1: act = silu(y@gp^T) * (y@up^T), gathered rows =====================
__global__ __launch_bounds__(256) void moe_mlp1_kernel(
    const float* __restrict__ Y,
    const float* __restrict__ Gp, const float* __restrict__ Up,
    const int* __restrict__ etok, const int* __restrict__ base,
    const int* __restrict__ pcnt, float* __restrict__ act)
{
  int seg = blockIdx.z;
  if ((int)(blockIdx.y * 64) >= pcnt[seg]) return;
  int e = seg & 7;
  __shared__ __align__(16) float As[16][68];
  __shared__ __align__(16) float Gs[16][68];
  __shared__ __align__(16) float Us[16][68];
  int t = threadIdx.x;
  int row0 = base[seg] + blockIdx.y * 64;
  int n0 = blockIdx.x * 64;
  int lm = t >> 2, lk = (t & 3) << 2;
  int tx = t & 15, ty = t >> 4;
  int tok = etok[row0 + lm];
  const float* ap = (tok >= 0) ? (Y + (size_t)tok * ND + lk) : nullptr;
  const float* gp = Gp + ((size_t)e * NFE + n0 + lm) * ND + lk;
  const float* up = Up + ((size_t)e * NFE + n0 + lm) * ND + lk;
  float ag[4][4] = {}, au[4][4] = {};
  for (int k0 = 0; k0 < ND; k0 += 16) {
    float4 av = ap ? *(const float4*)(ap + k0) : make_float4(0.f, 0.f, 0.f, 0.f);
    float4 gv = *(const float4*)(gp + k0);
    float4 uv = *(const float4*)(up + k0);
    As[lk+0][lm]=av.x; As[lk+1][lm]=av.y; As[lk+2][lm]=av.z; As[lk+3][lm]=av.w;
    Gs[lk+0][lm]=gv.x; Gs[lk+1][lm]=gv.y; Gs[lk+2][lm]=gv.z; Gs[lk+3][lm]=gv.w;
    Us[lk+0][lm]=uv.x; Us[lk+1][lm]=uv.y; Us[lk+2][lm]=uv.z; Us[lk+3][lm]=uv.w;
    __syncthreads();
#pragma unroll
    for (int k = 0; k < 16; k++) {
      float a[4], g[4], u[4];
      *(float4*)a = *(const float4*)&As[k][ty << 2];
      *(float4*)g = *(const float4*)&Gs[k][tx << 2];
      *(float4*)u = *(const float4*)&Us[k][tx << 2];
#pragma unroll
      for (int i = 0; i < 4; i++)
#pragma unroll
        for (int j = 0; j < 4; j++) { ag[i][j] += a[i]*g[j]; au[i][j] += a[i]*u[j]; }
    }
    __syncthreads();
  }
#pragma unroll
  for (int i = 0; i < 4; i++) {
    size_t r = (size_t)row0 + (ty << 2) + i;
#pragma unroll
    for (int j = 0; j < 4; j++) {
      float g = ag[i][j], u = au[i][j];
      float s = g / (1.f + __expf(-g));
      act[r * NFE + n0 + (tx << 2) + j] = s * u;
    }
  }
}

// ===================== MoE down: out[token] += w * (act @ dp^T) =====================
__global__ __launch_bounds__(256) void moe_down_kernel(
    const float* __restrict__ act, const float* __restrict__ Dp,
    const int* __restrict__ etok, const float* __restrict__ ew,
    const int* __restrict__ base, const int* __restrict__ pcnt,
    int slot, float* __restrict__ out)
{
  int e = blockIdx.z;
  int seg = slot * 8 + e;
  if ((int)(blockIdx.y * 64) >= pcnt[seg]) return;
  __shared__ __align__(16) float As[16][68];
  __shared__ __align__(16) float Ws[16][68];
  int t = threadIdx.x;
  int row0 = base[seg] + blockIdx.y * 64;
  int n0 = blockIdx.x * 64;
  int lm = t >> 2, lk = (t & 3) << 2;
  int tx = t & 15, ty = t >> 4;
  const float* ap = act + (size_t)(row0 + lm) * NFE + lk;
  const float* wp = Dp + ((size_t)e * ND + n0 + lm) * NFE + lk;
  float acc[4][4] = {};
  for (int k0 = 0; k0 < NFE; k0 += 16) {
    float4 av = *(const float4*)(ap + k0);
    float4 wv = *(const float4*)(wp + k0);
    As[lk+0][lm]=av.x; As[lk+1][lm]=av.y; As[lk+2][lm]=av.z; As[lk+3][lm]=av.w;
    Ws[lk+0][lm]=wv.x; Ws[lk+1][lm]=wv.y; Ws[lk+2][lm]=wv.z; Ws[lk+3][lm]=wv.w;
    __syncthreads();
#pragma unroll
    for (int k = 0; k < 16; k++) {
      float a[4], b[4];
      *(float4*)a = *(const float4*)&As[k][ty << 2];
      *(float4*)b = *(const float4*)&Ws[k][tx << 2];
#pragma unroll
      for (int i = 0; i < 4; i++)
#pragma unroll
        for (int j = 0; j < 4; j++) acc[i][j] += a[i] * b[j];
    }
    __syncthreads();
  }
#pragma unroll
  for (int i = 0; i < 4; i++) {
    int r = row0 + (ty << 2) + i;
    int tok = etok[r];
    if (tok >= 0) {
      float w = ew[r];
      float* op = out + (size_t)tok * ND + n0 + (tx << 2);
#pragma unroll
      for (int j = 0; j < 4; j++) op[j] += w * acc[i][j];
    }
  }
}

// ===================== launch =====================
extern "C" void kernel_launch(void* const* d_in, const int* in_sizes, int n_in,
                              void* d_out, int out_size, void* d_ws, size_t ws_size,
                              hipStream_t stream) {
  const float* hidden    = (const float*)d_in[0];
  // d_in[1] attention_mask: all-ones in this problem; causal mask handled in-kernel
  const float* in_ln_w   = (const float*)d_in[2];
  const float* post_ln_w = (const float*)d_in[3];
  const float* wq_a_w    = (const float*)d_in[4];
  const float* wq_a_b    = (const float*)d_in[5];
  const float* q_norm_w  = (const float*)d_in[6];
  const float* wq_b_w    = (const float*)d_in[7];
  const float* wq_b_b    = (const float*)d_in[8];
  const float* wkv_a_w   = (const float*)d_in[9];
  const float* wkv_a_b   = (const float*)d_in[10];
  const float* kv_norm_w = (const float*)d_in[11];
  const float* wkv_b_w   = (const float*)d_in[12];
  const float* wo_w      = (const float*)d_in[13];
  const float* wo_b      = (const float*)d_in[14];
  const float* gate_w    = (const float*)d_in[15];
  const float* gate_b    = (const float*)d_in[16];
  const float* gate_proj = (const float*)d_in[17];
  const float* up_proj   = (const float*)d_in[18];
  const float* down_proj = (const float*)d_in[19];

  float* ws = (float*)d_ws;
  if (ws_size < WS_FLOATS * sizeof(float)) return;  // workspace insufficient

  float* x     = ws + OFF_X;
  float* qa    = ws + OFF_QA;
  float* qbuf  = ws + OFF_QB;
  float* kvp   = ws + OFF_KVP;
  float* kvn   = ws + OFF_KVN;
  float* hbuf  = ws + OFF_H;
  float* ybuf  = ws + OFF_Y;
  float* tkw   = ws + OFF_TKW;
  float* ew    = ws + OFF_EW;
  float* actb  = ws + OFF_ACT;    // alias of qa..kvp region
  float* oproj = ws + OFF_OPROJ;  // alias of x
  int* ib   = (int*)(ws + OFF_INT);
  int* tke  = ib + IOFF_TKE;
  int* etok = ib + IOFF_ETOK;
  int* cnt  = ib + IOFF_CNT;
  int* cnt2 = cnt + 16;
  int* base = cnt + 32;
  int* pcnt = cnt + 48;

  float* out    = (float*)d_out;        // (B,S,D)
  float* logits = out + (size_t)NTOK * ND;  // (B*S, 8)

  // 1. x = rmsnorm(hidden, in_ln_w)
  rmsnorm_kernel<4><<<NTOK, 256, 0, stream>>>(hidden, ND, in_ln_w, x, ND);
  // 2. q_pre = x @ wq_a^T + b
  gemm_nt<<<dim3(8, 64), 256, 0, stream>>>(x, ND, wq_a_w, ND, wq_a_b, nullptr,
                                           qa, 512, nullptr, 512, ND);
  // 3. kvp = x @ wkv_a^T + b
  gemm_nt<<<dim3(5, 64), 256, 0, stream>>>(x, ND, wkv_a_w, ND, wkv_a_b, nullptr,
                                           kvp, 288, nullptr, 288, ND);
  // 4. q = rmsnorm(q_pre) in-place
  rmsnorm_kernel<2><<<NTOK, 256, 0, stream>>>(qa, 512, q_norm_w, qa, 512);
  // 5. kv = rmsnorm(kvp[:, :256])
  rmsnorm_kernel<1><<<NTOK, 256, 0, stream>>>(kvp, 288, kv_norm_w, kvn, 256);
  // 6. qbuf = q @ wq_b^T + b    (B,S,H,96)
  gemm_nt<<<dim3(24, 64), 256, 0, stream>>>(qa, 512, wq_b_w, 512, wq_b_b, nullptr,
                                            qbuf, 1536, nullptr, 1536, 512);
  // 7/8. RoPE in-place
  rope_q_kernel<<<4096, 256, 0, stream>>>(qbuf);
  rope_k_kernel<<<256, 256, 0, stream>>>(kvp);
  // 9. attention -> oproj
  {
    size_t smem = (size_t)(64 * QSTR + 32 * KSTR + 64 * SSTR + 192) * sizeof(float);
    hipFuncSetAttribute((const void*)attn_kernel,
                        hipFuncAttributeMaxDynamicSharedMemorySize, (int)smem);
    attn_kernel<<<dim3(NS / 64, NH, NB), 256, smem, stream>>>(qbuf, kvn, kvp, wkv_b_w, oproj);
  }
  // 10. h = oproj @ wo^T + wo_b + hidden  (also seeds d_out with h)
  gemm_nt<<<dim3(16, 64), 256, 0, stream>>>(oproj, ND, wo_w, ND, wo_b, hidden,
                                            hbuf, ND, out, ND, ND);
  // 11. y = rmsnorm(h, post_ln_w)
  rmsnorm_kernel<4><<<NTOK, 256, 0, stream>>>(hbuf, ND, post_ln_w, ybuf, ND);
  // 12. logits
  gate_kernel<<<NTOK, 256, 0, stream>>>(ybuf, gate_w, gate_b, logits);
  // 13. zero counters, -1 entry tokens
  hipMemsetAsync(cnt, 0, 32 * sizeof(int), stream);
  hipMemsetAsync(etok, 0xFF, 9216 * sizeof(int), stream);
  // 14-16. gating -> gathered entry lists
  topk_kernel<<<16, 256, 0, stream>>>(logits, tke, tkw, cnt);
  offsets_kernel<<<1, 64, 0, stream>>>(cnt, base, pcnt);
  scatter_kernel<<<16, 256, 0, stream>>>(tke, tkw, base, cnt2, etok, ew);
  // 17. act = silu(y@gp^T)*(y@up^T) over gathered rows
  moe_mlp1_kernel<<<dim3(16, 64, 16), 256, 0, stream>>>(ybuf, gate_proj, up_proj,
                                                        etok, base, pcnt, actb);
  // 18/19. out += w * (act @ dp^T), slot 0 then slot 1 (no write conflicts within a slot)
  moe_down_kernel<<<dim3(16, 64, 8), 256, 0, stream>>>(actb, down_proj, etok, ew,
                                                       base, pcnt, 0, out);
  moe_down_kernel<<<dim3(16, 64, 8), 256, 0, stream>>>(actb, down_proj, etok, ew,
                                                       base, pcnt, 1, out);
}

// Round 2
// 1891.725 us; speedup vs baseline: 1.9997x; 1.9997x over previous
//
#include <hip/hip_runtime.h>
#include <math.h>

// ===== problem constants =====
#define NB   4
#define NS   1024
#define ND   1024
#define NH   16
#define NTOK 4096     // NB*NS
#define NFE  1024

// ===== workspace layout (float offsets) =====
static constexpr size_t OFF_X    = 0;                       // 4096*1024  x ; later aliased as o_proj
static constexpr size_t OFF_QA   = OFF_X   + 4194304;       // 4096*512
static constexpr size_t OFF_QB   = OFF_QA  + 2097152;       // 4096*1536
static constexpr size_t OFF_KVP  = OFF_QB  + 6291456;       // 4096*288
static constexpr size_t OFF_KVN  = OFF_KVP + 1179648;       // 4096*256
static constexpr size_t OFF_H    = OFF_KVN + 1048576;       // 4096*1024
static constexpr size_t OFF_Y    = OFF_H   + 4194304;       // 4096*1024
static constexpr size_t OFF_TKW  = OFF_Y   + 4194304;       // 8192
static constexpr size_t OFF_EW   = OFF_TKW + 8192;          // 9216
static constexpr size_t OFF_INT  = OFF_EW  + 9216;          // int region below
static constexpr size_t IOFF_TKE  = 0;                      // 8192 ints
static constexpr size_t IOFF_ETOK = 8192;                   // 9216 ints
static constexpr size_t IOFF_CNT  = 17408;                  // 16 cnt | 16 cnt2 | 16 base | 16 pcnt
static constexpr size_t WS_FLOATS = OFF_INT + 17472;
// aliases (lifetimes don't overlap):
static constexpr size_t OFF_ACT   = OFF_QA;   // 9216*1024 spans QA..KVP region (ends < OFF_KVN)
static constexpr size_t OFF_OPROJ = OFF_X;    // x is dead once attention runs

// ===================== RMSNorm =====================
template<int PER>
__global__ __launch_bounds__(256) void rmsnorm_kernel(
    const float* in, int istr, const float* w, float* out, int ostr)
{
  int row = blockIdx.x, t = threadIdx.x;
  const float* ip = in + (size_t)row * istr;
  float v[PER];
  float ss = 0.f;
#pragma unroll
  for (int i = 0; i < PER; i++) { v[i] = ip[t + i*256]; ss += v[i]*v[i]; }
#pragma unroll
  for (int k = 1; k < 64; k <<= 1) ss += __shfl_xor(ss, k);
  __shared__ float red[4];
  if ((t & 63) == 0) red[t >> 6] = ss;
  __syncthreads();
  float tot = red[0] + red[1] + red[2] + red[3];
  float inv = rsqrtf(tot * (1.f / (PER * 256)) + 1e-6f);
  float* op = out + (size_t)row * ostr;
#pragma unroll
  for (int i = 0; i < PER; i++) op[t + i*256] = v[i] * inv * w[t + i*256];
}

// ===================== generic f32 GEMM: C = A @ W^T (+bias)(+resid) =====================
__global__ __launch_bounds__(256) void gemm_nt(
    const float* __restrict__ A, int lda,
    const float* __restrict__ W, int ldw,
    const float* __restrict__ bias,
    const float* __restrict__ resid,
    float* __restrict__ C, int ldc,
    float* __restrict__ C2,
    int N, int K)
{
  __shared__ __align__(16) float As[16][68];
  __shared__ __align__(16) float Ws[16][68];
  int t = threadIdx.x;
  int m0 = blockIdx.y * 64, n0 = blockIdx.x * 64;
  int lm = t >> 2, lk = (t & 3) << 2;
  int tx = t & 15, ty = t >> 4;
  const float* ap = A + (size_t)(m0 + lm) * lda + lk;
  bool wok = (n0 + lm) < N;
  const float* wp = wok ? (W + (size_t)(n0 + lm) * ldw + lk) : nullptr;
  float acc[4][4] = {};
  for (int k0 = 0; k0 < K; k0 += 16) {
    float4 av = *(const float4*)(ap + k0);
    float4 wv = wok ? *(const float4*)(wp + k0) : make_float4(0.f, 0.f, 0.f, 0.f);
    As[lk+0][lm] = av.x; As[lk+1][lm] = av.y; As[lk+2][lm] = av.z; As[lk+3][lm] = av.w;
    Ws[lk+0][lm] = wv.x; Ws[lk+1][lm] = wv.y; Ws[lk+2][lm] = wv.z; Ws[lk+3][lm] = wv.w;
    __syncthreads();
#pragma unroll
    for (int k = 0; k < 16; k++) {
      float a[4], b[4];
      *(float4*)a = *(const float4*)&As[k][ty << 2];
      *(float4*)b = *(const float4*)&Ws[k][tx << 2];
#pragma unroll
      for (int i = 0; i < 4; i++)
#pragma unroll
        for (int j = 0; j < 4; j++) acc[i][j] += a[i] * b[j];
    }
    __syncthreads();
  }
#pragma unroll
  for (int i = 0; i < 4; i++) {
    int m = m0 + (ty << 2) + i;
#pragma unroll
    for (int j = 0; j < 4; j++) {
      int n = n0 + (tx << 2) + j;
      if (n < N) {
        float v = acc[i][j];
        if (bias)  v += bias[n];
        size_t off = (size_t)m * ldc + n;
        if (resid) v += resid[off];
        C[off] = v;
        if (C2) C2[off] = v;
      }
    }
  }
}

// ===================== RoPE =====================
__global__ __launch_bounds__(256) void rope_q_kernel(float* qbuf)
{
  int id = blockIdx.x * 256 + threadIdx.x;     // NTOK*NH*16
  int d = id & 15;
  int h = (id >> 4) & 15;
  int sr = id >> 8;                            // 0..4095
  int s = sr & (NS - 1);
  float inv = __expf(-(float)(2 * d) * (9.210340371976184f / 32.f)); // 10000^(-2d/32)
  float fr = (float)s * inv;
  float sn, cs; sincosf(fr, &sn, &cs);
  float* p = qbuf + (size_t)sr * 1536 + h * 96 + 64;
  float x1 = p[d], x2 = p[d + 16];
  p[d]      = x1 * cs - x2 * sn;
  p[d + 16] = x2 * cs + x1 * sn;
}

__global__ __launch_bounds__(256) void rope_k_kernel(float* kvp)
{
  int id = blockIdx.x * 256 + threadIdx.x;     // NTOK*16
  int d = id & 15;
  int sr = id >> 4;
  int s = sr & (NS - 1);
  float inv = __expf(-(float)(2 * d) * (9.210340371976184f / 32.f));
  float fr = (float)s * inv;
  float sn, cs; sincosf(fr, &sn, &cs);
  float* p = kvp + (size_t)sr * 288 + 256;
  float x1 = p[d], x2 = p[d + 16];
  p[d]      = x1 * cs - x2 * sn;
  p[d + 16] = x2 * cs + x1 * sn;
}

// ===================== MLA flash attention (bf16 MFMA) =====================
// grid (S/64, H, B), 256 threads (4 waves), dynamic LDS 81408 B.
// Swapped-operand scores: S^T = K_tile (A) x Q^T (B) via mfma_f32_16x16x32_bf16;
// each lane owns one q-column -> in-register online softmax with 2 shfl_xor.
// PV: A = P (from swizzled LDS round-trip), B = V from feature-major vt.
#define QPAD 296      // bf16 row stride for qs/ks: 592 B (16-mult, bank stride 20 mod 32)
#define VPAD 40       // bf16 row stride for vt: 80 B
#define OSTR 260      // f32 row stride for o_lds
typedef __attribute__((ext_vector_type(8))) short bf16x8_t;
typedef __attribute__((ext_vector_type(4))) float f32x4_t;

__device__ __forceinline__ unsigned pack2(float a, float b) {
  union { float f; unsigned u; } x, y; x.f = a; y.f = b;
  unsigned lo = (x.u + 0x7fffu + ((x.u >> 16) & 1u)) >> 16;
  unsigned hi = (y.u + 0x7fffu + ((y.u >> 16) & 1u)) & 0xffff0000u;
  return (lo & 0xffffu) | hi;
}
__device__ __forceinline__ short f2bfs(float f) {
  union { float f; unsigned u; } x; x.f = f;
  return (short)((x.u + 0x7fffu + ((x.u >> 16) & 1u)) >> 16);
}

__global__ __launch_bounds__(256) void attn_kernel(
    const float* __restrict__ qbuf,  // (NTOK, H*96)
    const float* __restrict__ kvn,   // (NTOK, 256)
    const float* __restrict__ kvp,   // (NTOK, 288), pe at +256
    const float* __restrict__ wkvb,  // (H*128, 256)
    float* __restrict__ oproj)       // (NTOK, H*64)
{
  extern __shared__ float4 smem_f4[];
  short* qs = (short*)smem_f4;        // [64][QPAD] bf16: q_abs(256)|q_pe(32), pre-scaled
  short* ks = qs + 64 * QPAD;         // [32][QPAD] bf16: kv(256)|pe(32) row-major
  short* vt = qs + 96 * QPAD;         // [256][VPAD] bf16: V feature-major
  short* ps = vt + 256 * VPAD;        // [64][32] bf16, 16B-granule XOR swizzled
  float* o_lds = (float*)smem_f4;     // phase 2: [64][OSTR] f32 (overlaps qs/ks/vt)
  float* qn = (float*)ks;             // prologue scratch: [64][68] f32 (fits in ks)

  int qb = (NS / 64 - 1) - blockIdx.x;   // reversed: heavy (late) q-blocks first
  int h = blockIdx.y, b = blockIdx.z;
  int t = threadIdx.x;
  int row0 = b * NS + qb * 64;
  const float scale = 0.10206207261596577f;  // 1/sqrt(96)

  // ---- prologue 0a: q_nope (scaled) -> qn scratch; q_pe (scaled) -> qs[., 256:288]
  for (int idx = t; idx < 64 * 96; idx += 256) {
    int r = idx / 96, c = idx % 96;
    float v = qbuf[(size_t)(row0 + r) * 1536 + h * 96 + c] * scale;
    if (c < 64) qn[r * 68 + c] = v;
    else        qs[r * QPAD + 256 + (c - 64)] = f2bfs(v);
  }
  __syncthreads();
  // ---- prologue 0b: qs[:, 0:256] = q_nope @ wkv_b[h, 0:64, :]  (bf16 out)
  {
    int cx = t & 63, ry = t >> 6;
    float a[16][4] = {};
    const float* wb = wkvb + (size_t)h * 128 * 256 + cx * 4;
    for (int k = 0; k < 64; k++) {
      float4 wv = *(const float4*)(wb + (size_t)k * 256);
#pragma unroll
      for (int r = 0; r < 16; r++) {
        float qv = qn[(ry * 16 + r) * 68 + k];
        a[r][0] += qv * wv.x; a[r][1] += qv * wv.y; a[r][2] += qv * wv.z; a[r][3] += qv * wv.w;
      }
    }
    __syncthreads();   // qn reads done before ks staging clobbers the region
#pragma unroll
    for (int r = 0; r < 16; r++) {
      uint2 pk; pk.x = pack2(a[r][0], a[r][1]); pk.y = pack2(a[r][2], a[r][3]);
      *(uint2*)&qs[(ry * 16 + r) * QPAD + cx * 4] = pk;
    }
  }
  __syncthreads();     // qs fully ready

  int lane = t & 63, wv_ = t >> 6;
  int lrow = lane & 15, lg = lane >> 4;
  float m_run = -1e30f, l_run = 0.f;
  f32x4_t acco[16];
#pragma unroll
  for (int n = 0; n < 16; n++) acco[n] = (f32x4_t){0.f, 0.f, 0.f, 0.f};

  int nkb = 2 * qb + 2;
  for (int kb = 0; kb < nkb; kb++) {
    int key0 = kb * 32;
    size_t tb = (size_t)b * NS + key0;
    // ---- stage ks: 32x256 kv (f32->bf16) + 32x32 pe, row-major
#pragma unroll
    for (int it = 0; it < 8; it++) {
      int idx = it * 256 + t;
      int key = idx >> 6, f4 = (idx & 63) << 2;
      float4 v = *(const float4*)(kvn + (tb + key) * 256 + f4);
      uint2 pk; pk.x = pack2(v.x, v.y); pk.y = pack2(v.z, v.w);
      *(uint2*)&ks[key * QPAD + f4] = pk;
    }
    {
      int key = t >> 3, c4 = (t & 7) << 2;
      float4 v = *(const float4*)(kvp + (tb + key) * 288 + 256 + c4);
      uint2 pk; pk.x = pack2(v.x, v.y); pk.y = pack2(v.z, v.w);
      *(uint2*)&ks[key * QPAD + 256 + c4] = pk;
    }
    // ---- stage vt: V feature-major (direct gather from kvn)
#pragma unroll
    for (int it = 0; it < 8; it++) {
      int idx = it * 256 + t;
      int feat = idx & 255, k4 = (idx >> 8) << 2;
      const float* s0 = kvn + (tb + k4) * 256 + feat;
      float a0 = s0[0], a1 = s0[256], a2 = s0[512], a3 = s0[768];
      uint2 pk; pk.x = pack2(a0, a1); pk.y = pack2(a2, a3);
      *(uint2*)&vt[feat * VPAD + k4] = pk;
    }
    __syncthreads();
    // ---- scores: S^T tiles (2 key-tiles x this wave's q-tile), K-dim 288 = 9 steps
    f32x4_t s0a = {0.f, 0.f, 0.f, 0.f}, s1a = {0.f, 0.f, 0.f, 0.f};
#pragma unroll
    for (int kk = 0; kk < 9; kk++) {
      bf16x8_t bq = *(const bf16x8_t*)&qs[(16 * wv_ + lrow) * QPAD + kk * 32 + lg * 8];
      bf16x8_t a0 = *(const bf16x8_t*)&ks[lrow * QPAD + kk * 32 + lg * 8];
      bf16x8_t a1 = *(const bf16x8_t*)&ks[(16 + lrow) * QPAD + kk * 32 + lg * 8];
      s0a = __builtin_amdgcn_mfma_f32_16x16x32_bf16(a0, bq, s0a, 0, 0, 0);
      s1a = __builtin_amdgcn_mfma_f32_16x16x32_bf16(a1, bq, s1a, 0, 0, 0);
    }
    // ---- causal mask + online softmax (lane owns q-column qg)
    int qg = qb * 64 + 16 * wv_ + lrow;
    float sv[8];
#pragma unroll
    for (int r = 0; r < 4; r++) {
      sv[r]     = (key0 + 4 * lg + r      <= qg) ? s0a[r] : -1e30f;
      sv[4 + r] = (key0 + 16 + 4 * lg + r <= qg) ? s1a[r] : -1e30f;
    }
    float mx = sv[0];
#pragma unroll
    for (int i = 1; i < 8; i++) mx = fmaxf(mx, sv[i]);
    mx = fmaxf(mx, __shfl_xor(mx, 16));
    mx = fmaxf(mx, __shfl_xor(mx, 32));
    float mnew = fmaxf(m_run, mx);
    float al = __expf(m_run - mnew);
    float sum = 0.f;
#pragma unroll
    for (int i = 0; i < 8; i++) { sv[i] = __expf(sv[i] - mnew); sum += sv[i]; }
    sum += __shfl_xor(sum, 16);
    sum += __shfl_xor(sum, 32);
    l_run = l_run * al + sum;
    m_run = mnew;
    // ---- write P (bf16) to ps, XOR-swizzled at 16B granules (row q, 64B/row)
    {
      int q = 16 * wv_ + lrow, swz = q & 3;
      int g0 = lg >> 1, h0 = lg & 1;
      uint2 p0; p0.x = pack2(sv[0], sv[1]); p0.y = pack2(sv[2], sv[3]);
      uint2 p1; p1.x = pack2(sv[4], sv[5]); p1.y = pack2(sv[6], sv[7]);
      char* pr = (char*)ps + q * 64;
      *(uint2*)(pr + ((g0 ^ swz) * 16 + h0 * 8))       = p0;   // keys 4lg..+3
      *(uint2*)(pr + (((2 + g0) ^ swz) * 16 + h0 * 8)) = p1;   // keys 16+4lg..+3
    }
    // ---- rescale O by alpha (acco row q = 16w + 4lg + r; alpha lives in lane 4lg+r)
    {
      float al0 = __shfl(al, 4 * lg + 0);
      float al1 = __shfl(al, 4 * lg + 1);
      float al2 = __shfl(al, 4 * lg + 2);
      float al3 = __shfl(al, 4 * lg + 3);
#pragma unroll
      for (int n = 0; n < 16; n++) {
        acco[n][0] *= al0; acco[n][1] *= al1; acco[n][2] *= al2; acco[n][3] *= al3;
      }
    }
    // ---- PV: O += P x V (A-frag from ps, B-frags from vt)
    {
      int q = 16 * wv_ + lrow;
      bf16x8_t ap = *(const bf16x8_t*)((char*)ps + q * 64 + ((lg ^ (q & 3)) * 16));
#pragma unroll
      for (int n = 0; n < 16; n++) {
        bf16x8_t bv = *(const bf16x8_t*)&vt[(n * 16 + lrow) * VPAD + lg * 8];
        acco[n] = __builtin_amdgcn_mfma_f32_16x16x32_bf16(ap, bv, acco[n], 0, 0, 0);
      }
    }
    __syncthreads();   // all PV reads done before next staging / o_lds writes
  }
  // ---- normalize + store O (f32) to o_lds
  {
    float li = 1.f / l_run;
    float l0 = __shfl(li, 4 * lg + 0);
    float l1 = __shfl(li, 4 * lg + 1);
    float l2 = __shfl(li, 4 * lg + 2);
    float l3 = __shfl(li, 4 * lg + 3);
#pragma unroll
    for (int n = 0; n < 16; n++) {
      int fc = n * 16 + lrow;
      o_lds[(16 * wv_ + 4 * lg + 0) * OSTR + fc] = acco[n][0] * l0;
      o_lds[(16 * wv_ + 4 * lg + 1) * OSTR + fc] = acco[n][1] * l1;
      o_lds[(16 * wv_ + 4 * lg + 2) * OSTR + fc] = acco[n][2] * l2;
      o_lds[(16 * wv_ + 4 * lg + 3) * OSTR + fc] = acco[n][3] * l3;
    }
  }
  __syncthreads();
  // ---- epilogue: oproj[r][d] = sum_c o[r][c] * wkv_b[h,64+d,c]
  {
    int dx = t & 15, ty2 = t >> 4;
    float pr[4][4] = {};
    const float* wb = wkvb + (size_t)(h * 128 + 64) * 256;
    for (int c = 0; c < 256; c += 4) {
      float4 w0 = *(const float4*)(wb + (size_t)(dx * 4 + 0) * 256 + c);
      float4 w1 = *(const float4*)(wb + (size_t)(dx * 4 + 1) * 256 + c);
      float4 w2 = *(const float4*)(wb + (size_t)(dx * 4 + 2) * 256 + c);
      float4 w3 = *(const float4*)(wb + (size_t)(dx * 4 + 3) * 256 + c);
#pragma unroll
      for (int i = 0; i < 4; i++) {
        float4 ov = *(const float4*)&o_lds[(ty2 * 4 + i) * OSTR + c];
        pr[i][0] += ov.x*w0.x + ov.y*w0.y + ov.z*w0.z + ov.w*w0.w;
        pr[i][1] += ov.x*w1.x + ov.y*w1.y + ov.z*w1.z + ov.w*w1.w;
        pr[i][2] += ov.x*w2.x + ov.y*w2.y + ov.z*w2.z + ov.w*w2.w;
        pr[i][3] += ov.x*w3.x + ov.y*w3.y + ov.z*w3.z + ov.w*w3.w;
      }
    }
#pragma unroll
    for (int i = 0; i < 4; i++)
#pragma unroll
      for (int j = 0; j < 4; j++)
        oproj[(size_t)(row0 + ty2 * 4 + i) * 1024 + h * 64 + dx * 4 + j] = pr[i][j];
  }
}

// ===================== gate logits =====================
__global__ __launch_bounds__(256) void gate_kernel(
    const float* __restrict__ Y, const float* __restrict__ gw,
    const float* __restrict__ gb, float* __restrict__ logits)
{
  __shared__ __align__(16) float ly[1024];
  int tok = blockIdx.x, t = threadIdx.x;
  *(float4*)&ly[t * 4] = *(const float4*)(Y + (size_t)tok * ND + t * 4);
  __syncthreads();
  int e = t >> 5, lane = t & 31;
  const float* w = gw + (size_t)e * ND;
  float ss = 0.f;
  for (int d = lane; d < ND; d += 32) ss += ly[d] * w[d];
#pragma unroll
  for (int k = 16; k >= 1; k >>= 1) ss += __shfl_xor(ss, k);
  if (lane == 0) logits[(size_t)tok * 8 + e] = ss + gb[e];
}

// ===================== top-2 gating + counts =====================
__global__ __launch_bounds__(256) void topk_kernel(
    const float* __restrict__ logits, int* __restrict__ tke,
    float* __restrict__ tkw, int* __restrict__ cnt)
{
  int tok = blockIdx.x * 256 + threadIdx.x;
  if (tok >= NTOK) return;
  float l[8];
#pragma unroll
  for (int e2 = 0; e2 < 8; e2++) l[e2] = logits[(size_t)tok * 8 + e2];
  float v0 = l[0]; int e0 = 0;
#pragma unroll
  for (int e2 = 1; e2 < 8; e2++) if (l[e2] > v0) { v0 = l[e2]; e0 = e2; }
  float v1 = -INFINITY; int e1 = 0;
#pragma unroll
  for (int e2 = 0; e2 < 8; e2++) if (e2 != e0 && l[e2] > v1) { v1 = l[e2]; e1 = e2; }
  float x = __expf(v1 - v0);
  float w0 = 1.f / (1.f + x);
  tke[tok * 2]     = e0; tke[tok * 2 + 1] = e1;
  tkw[tok * 2]     = w0; tkw[tok * 2 + 1] = 1.f - w0;
  atomicAdd(&cnt[e0], 1);
  atomicAdd(&cnt[8 + e1], 1);
}

__global__ void offsets_kernel(const int* cnt, int* base, int* pcnt)
{
  if (threadIdx.x == 0 && blockIdx.x == 0) {
    int cum = 0;
    for (int s2 = 0; s2 < 16; s2++) {
      int p = (cnt[s2] + 63) & ~63;
      base[s2] = cum; pcnt[s2] = p; cum += p;
    }
  }
}

__global__ __launch_bounds__(256) void scatter_kernel(
    const int* __restrict__ tke, const float* __restrict__ tkw,
    const int* __restrict__ base, int* cnt2,
    int* __restrict__ etok, float* __restrict__ ew)
{
  int tok = blockIdx.x * 256 + threadIdx.x;
  if (tok >= NTOK) return;
#pragma unroll
  for (int k = 0; k < 2; k++) {
    int e = tke[tok * 2 + k];
    int seg = k * 8 + e;
    int pos = atomicAdd(&cnt2[seg], 1);
    int row = base[seg] + pos;
    etok[row] = tok;
    ew[row] = tkw[tok * 2 + k];
  }
}

// ===================== MoE mlp1: act = silu(y@gp^T) * (y@up^T), gathered rows =====================
__global__ __launch_bounds__(256) void moe_mlp1_kernel(
    const float* __restrict__ Y,
    const float* __restrict__ Gp, const float* __restrict__ Up,
    const int* __restrict__ etok, const int* __restrict__ base,
    const int* __restrict__ pcnt, float* __restrict__ act)
{
  int seg = blockIdx.z;
  if ((int)(blockIdx.y * 64) >= pcnt[seg]) return;
  int e = seg & 7;
  __shared__ __align__(16) float As[16][68];
  __shared__ __align__(16) float Gs[16][68];
  __shared__ __align__(16) float Us[16][68];
  int t = threadIdx.x;
  int row0 = base[seg] + blockIdx.y * 64;
  int n0 = blockIdx.x * 64;
  int lm = t >> 2, lk = (t & 3) << 2;
  int tx = t & 15, ty = t >> 4;
  int tok = etok[row0 + lm];
  const float* ap = (tok >= 0) ? (Y + (size_t)tok * ND + lk) : nullptr;
  const float* gp = Gp + ((size_t)e * NFE + n0 + lm) * ND + lk;
  const float* up = Up + ((size_t)e * NFE + n0 + lm) * ND + lk;
  float ag[4][4] = {}, au[4][4] = {};
  for (int k0 = 0; k0 < ND; k0 += 16) {
    float4 av = ap ? *(const float4*)(ap + k0) : make_float4(0.f, 0.f, 0.f, 0.f);
    float4 gv = *(const float4*)(gp + k0);
    float4 uv = *(const float4*)(up + k0);
    As[lk+0][lm]=av.x; As[lk+1][lm]=av.y; As[lk+2][lm]=av.z; As[lk+3][lm]=av.w;
    Gs[lk+0][lm]=gv.x; Gs[lk+1][lm]=gv.y; Gs[lk+2][lm]=gv.z; Gs[lk+3][lm]=gv.w;
    Us[lk+0][lm]=uv.x; Us[lk+1][lm]=uv.y; Us[lk+2][lm]=uv.z; Us[lk+3][lm]=uv.w;
    __syncthreads();
#pragma unroll
    for (int k = 0; k < 16; k++) {
      float a[4], g[4], u[4];
      *(float4*)a = *(const float4*)&As[k][ty << 2];
      *(float4*)g = *(const float4*)&Gs[k][tx << 2];
      *(float4*)u = *(const float4*)&Us[k][tx << 2];
#pragma unroll
      for (int i = 0; i < 4; i++)
#pragma unroll
        for (int j = 0; j < 4; j++) { ag[i][j] += a[i]*g[j]; au[i][j] += a[i]*u[j]; }
    }
    __syncthreads();
  }
#pragma unroll
  for (int i = 0; i < 4; i++) {
    size_t r = (size_t)row0 + (ty << 2) + i;
#pragma unroll
    for (int j = 0; j < 4; j++) {
      float g = ag[i][j], u = au[i][j];
      float s = g / (1.f + __expf(-g));
      act[r * NFE + n0 + (tx << 2) + j] = s * u;
    }
  }
}

// ===================== MoE down: out[token] += w * (act @ dp^T) =====================
__global__ __launch_bounds__(256) void moe_down_kernel(
    const float* __restrict__ act, const float* __restrict__ Dp,
    const int* __restrict__ etok, const float* __restrict__ ew,
    const int* __restrict__ base, const int* __restrict__ pcnt,
    int slot, float* __restrict__ out)
{
  int e = blockIdx.z;
  int seg = slot * 8 + e;
  if ((int)(blockIdx.y * 64) >= pcnt[seg]) return;
  __shared__ __align__(16) float As[16][68];
  __shared__ __align__(16) float Ws[16][68];
  int t = threadIdx.x;
  int row0 = base[seg] + blockIdx.y * 64;
  int n0 = blockIdx.x * 64;
  int lm = t >> 2, lk = (t & 3) << 2;
  int tx = t & 15, ty = t >> 4;
  const float* ap = act + (size_t)(row0 + lm) * NFE + lk;
  const float* wp = Dp + ((size_t)e * ND + n0 + lm) * NFE + lk;
  float acc[4][4] = {};
  for (int k0 = 0; k0 < NFE; k0 += 16) {
    float4 av = *(const float4*)(ap + k0);
    float4 wv = *(const float4*)(wp + k0);
    As[lk+0][lm]=av.x; As[lk+1][lm]=av.y; As[lk+2][lm]=av.z; As[lk+3][lm]=av.w;
    Ws[lk+0][lm]=wv.x; Ws[lk+1][lm]=wv.y; Ws[lk+2][lm]=wv.z; Ws[lk+3][lm]=wv.w;
    __syncthreads();
#pragma unroll
    for (int k = 0; k < 16; k++) {
      float a[4], b[4];
      *(float4*)a = *(const float4*)&As[k][ty << 2];
      *(float4*)b = *(const float4*)&Ws[k][tx << 2];
#pragma unroll
      for (int i = 0; i < 4; i++)
#pragma unroll
        for (int j = 0; j < 4; j++) acc[i][j] += a[i] * b[j];
    }
    __syncthreads();
  }
#pragma unroll
  for (int i = 0; i < 4; i++) {
    int r = row0 + (ty << 2) + i;
    int tok = etok[r];
    if (tok >= 0) {
      float w = ew[r];
      float* op = out + (size_t)tok * ND + n0 + (tx << 2);
#pragma unroll
      for (int j = 0; j < 4; j++) op[j] += w * acc[i][j];
    }
  }
}

// ===================== launch =====================
extern "C" void kernel_launch(void* const* d_in, const int* in_sizes, int n_in,
                              void* d_out, int out_size, void* d_ws, size_t ws_size,
                              hipStream_t stream) {
  const float* hidden    = (const float*)d_in[0];
  const float* in_ln_w   = (const float*)d_in[2];
  const float* post_ln_w = (const float*)d_in[3];
  const float* wq_a_w    = (const float*)d_in[4];
  const float* wq_a_b    = (const float*)d_in[5];
  const float* q_norm_w  = (const float*)d_in[6];
  const float* wq_b_w    = (const float*)d_in[7];
  const float* wq_b_b    = (const float*)d_in[8];
  const float* wkv_a_w   = (const float*)d_in[9];
  const float* wkv_a_b   = (const float*)d_in[10];
  const float* kv_norm_w = (const float*)d_in[11];
  const float* wkv_b_w   = (const float*)d_in[12];
  const float* wo_w      = (const float*)d_in[13];
  const float* wo_b      = (const float*)d_in[14];
  const float* gate_w    = (const float*)d_in[15];
  const float* gate_b    = (const float*)d_in[16];
  const float* gate_proj = (const float*)d_in[17];
  const float* up_proj   = (const float*)d_in[18];
  const float* down_proj = (const float*)d_in[19];

  float* ws = (float*)d_ws;
  if (ws_size < WS_FLOATS * sizeof(float)) return;

  float* x     = ws + OFF_X;
  float* qa    = ws + OFF_QA;
  float* qbuf  = ws + OFF_QB;
  float* kvp   = ws + OFF_KVP;
  float* kvn   = ws + OFF_KVN;
  float* hbuf  = ws + OFF_H;
  float* ybuf  = ws + OFF_Y;
  float* tkw   = ws + OFF_TKW;
  float* ew    = ws + OFF_EW;
  float* actb  = ws + OFF_ACT;
  float* oproj = ws + OFF_OPROJ;
  int* ib   = (int*)(ws + OFF_INT);
  int* tke  = ib + IOFF_TKE;
  int* etok = ib + IOFF_ETOK;
  int* cnt  = ib + IOFF_CNT;
  int* cnt2 = cnt + 16;
  int* base = cnt + 32;
  int* pcnt = cnt + 48;

  float* out    = (float*)d_out;
  float* logits = out + (size_t)NTOK * ND;

  rmsnorm_kernel<4><<<NTOK, 256, 0, stream>>>(hidden, ND, in_ln_w, x, ND);
  gemm_nt<<<dim3(8, 64), 256, 0, stream>>>(x, ND, wq_a_w, ND, wq_a_b, nullptr,
                                           qa, 512, nullptr, 512, ND);
  gemm_nt<<<dim3(5, 64), 256, 0, stream>>>(x, ND, wkv_a_w, ND, wkv_a_b, nullptr,
                                           kvp, 288, nullptr, 288, ND);
  rmsnorm_kernel<2><<<NTOK, 256, 0, stream>>>(qa, 512, q_norm_w, qa, 512);
  rmsnorm_kernel<1><<<NTOK, 256, 0, stream>>>(kvp, 288, kv_norm_w, kvn, 256);
  gemm_nt<<<dim3(24, 64), 256, 0, stream>>>(qa, 512, wq_b_w, 512, wq_b_b, nullptr,
                                            qbuf, 1536, nullptr, 1536, 512);
  rope_q_kernel<<<4096, 256, 0, stream>>>(qbuf);
  rope_k_kernel<<<256, 256, 0, stream>>>(kvp);
  {
    size_t smem = (size_t)(64*QPAD + 32*QPAD + 256*VPAD + 64*32) * sizeof(short); // 81408
    hipFuncSetAttribute((const void*)attn_kernel,
                        hipFuncAttributeMaxDynamicSharedMemorySize, (int)smem);
    attn_kernel<<<dim3(NS / 64, NH, NB), 256, smem, stream>>>(qbuf, kvn, kvp, wkv_b_w, oproj);
  }
  gemm_nt<<<dim3(16, 64), 256, 0, stream>>>(oproj, ND, wo_w, ND, wo_b, hidden,
                                            hbuf, ND, out, ND, ND);
  rmsnorm_kernel<4><<<NTOK, 256, 0, stream>>>(hbuf, ND, post_ln_w, ybuf, ND);
  gate_kernel<<<NTOK, 256, 0, stream>>>(ybuf, gate_w, gate_b, logits);
  hipMemsetAsync(cnt, 0, 32 * sizeof(int), stream);
  hipMemsetAsync(etok, 0xFF, 9216 * sizeof(int), stream);
  topk_kernel<<<16, 256, 0, stream>>>(logits, tke, tkw, cnt);
  offsets_kernel<<<1, 64, 0, stream>>>(cnt, base, pcnt);
  scatter_kernel<<<16, 256, 0, stream>>>(tke, tkw, base, cnt2, etok, ew);
  moe_mlp1_kernel<<<dim3(16, 64, 16), 256, 0, stream>>>(ybuf, gate_proj, up_proj,
                                                        etok, base, pcnt, actb);
  moe_down_kernel<<<dim3(16, 64, 8), 256, 0, stream>>>(actb, down_proj, etok, ew,
                                                       base, pcnt, 0, out);
  moe_down_kernel<<<dim3(16, 64, 8), 256, 0, stream>>>(actb, down_proj, etok, ew,
                                                       base, pcnt, 1, out);
}

// Round 3
// 1429.960 us; speedup vs baseline: 2.6454x; 1.3229x over previous
//
#include <hip/hip_runtime.h>
#include <math.h>

// ===== problem constants =====
#define NB   4
#define NS   1024
#define ND   1024
#define NH   16
#define NTOK 4096     // NB*NS
#define NFE  1024
#define ETOK_CAP 10240

// ===== workspace layout (float offsets) =====
static constexpr size_t OFF_X    = 0;                       // 4096*1024
static constexpr size_t OFF_QA   = OFF_X   + 4194304;       // 4096*512
static constexpr size_t OFF_QB   = OFF_QA  + 2097152;       // 4096*1536
static constexpr size_t OFF_KVP  = OFF_QB  + 6291456;       // 4096*288
static constexpr size_t OFF_KVN  = OFF_KVP + 1179648;       // 4096*256
static constexpr size_t OFF_H    = OFF_KVN + 1048576;       // 4096*1024
static constexpr size_t OFF_Y    = OFF_H   + 4194304;       // 4096*1024
static constexpr size_t OFF_TKW  = OFF_Y   + 4194304;       // 8192
static constexpr size_t OFF_EW   = OFF_TKW + 8192;          // ETOK_CAP
static constexpr size_t OFF_INT  = OFF_EW  + ETOK_CAP;
static constexpr size_t IOFF_TKE  = 0;                      // 8192 ints
static constexpr size_t IOFF_ETOK = 8192;                   // ETOK_CAP ints
static constexpr size_t IOFF_CNT  = 8192 + ETOK_CAP;        // 16 cnt | 16 cnt2 | 16 base | 16 pcnt
static constexpr size_t WS_FLOATS = OFF_INT + IOFF_CNT + 64;
// aliases (lifetimes don't overlap):
static constexpr size_t OFF_ACT   = OFF_QA;   // 10240*1024 f32 spans QA..KVN+ (all dead post-attn)
static constexpr size_t OFF_OPROJ = OFF_X;    // x is dead once attention runs

typedef __attribute__((ext_vector_type(8))) short bf16x8_t;
typedef __attribute__((ext_vector_type(4))) float f32x4_t;

__device__ __forceinline__ unsigned pack2(float a, float b) {
  union { float f; unsigned u; } x, y; x.f = a; y.f = b;
  unsigned lo = (x.u + 0x7fffu + ((x.u >> 16) & 1u)) >> 16;
  unsigned hi = (y.u + 0x7fffu + ((y.u >> 16) & 1u)) & 0xffff0000u;
  return (lo & 0xffffu) | hi;
}
__device__ __forceinline__ short f2bfs(float f) {
  union { float f; unsigned u; } x; x.f = f;
  return (short)((x.u + 0x7fffu + ((x.u >> 16) & 1u)) >> 16);
}

// ===================== RMSNorm =====================
template<int PER>
__global__ __launch_bounds__(256) void rmsnorm_kernel(
    const float* in, int istr, const float* w, float* out, int ostr)
{
  int row = blockIdx.x, t = threadIdx.x;
  const float* ip = in + (size_t)row * istr;
  float v[PER];
  float ss = 0.f;
#pragma unroll
  for (int i = 0; i < PER; i++) { v[i] = ip[t + i*256]; ss += v[i]*v[i]; }
#pragma unroll
  for (int k = 1; k < 64; k <<= 1) ss += __shfl_xor(ss, k);
  __shared__ float red[4];
  if ((t & 63) == 0) red[t >> 6] = ss;
  __syncthreads();
  float tot = red[0] + red[1] + red[2] + red[3];
  float inv = rsqrtf(tot * (1.f / (PER * 256)) + 1e-6f);
  float* op = out + (size_t)row * ostr;
#pragma unroll
  for (int i = 0; i < PER; i++) op[t + i*256] = v[i] * inv * w[t + i*256];
}

// ===================== bf16 MFMA GEMM: C = A @ W^T + bias (+resid) =====================
// 128x128 tile, BK=64, 256 threads (4 waves, each 64x64). f32 in, bf16 MFMA, f32 out.
// M must be multiple of 128; N guarded; K multiple of 64.
#define GSTR 72   // shorts per LDS row (64 data + 8 pad); 144B: 16B-aligned, ~2-way banks

template<bool RESID, bool C2F>
__global__ __launch_bounds__(256) void gemm_bf16(
    const float* __restrict__ A, int lda,
    const float* __restrict__ W, int ldw,
    const float* __restrict__ bias,
    const float* __restrict__ resid,
    float* __restrict__ C, int ldc,
    float* __restrict__ C2, int N, int K)
{
  __shared__ __align__(16) short As[128 * GSTR];
  __shared__ __align__(16) short Ws2[128 * GSTR];
  int t = threadIdx.x;
  int m0 = blockIdx.y * 128, n0 = blockIdx.x * 128;
  int srow = t >> 4, sf4 = (t & 15) * 4;     // staging: row srow(+16it), float-col sf4
  int lane = t & 63, w = t >> 6;
  int mw = (w >> 1) * 64, nw = (w & 1) * 64;
  int lr = lane & 15, lg = lane >> 4;

  float4 pa[8], pw[8];
  auto ldA = [&](int k0) {
#pragma unroll
    for (int it = 0; it < 8; it++)
      pa[it] = *(const float4*)(A + (size_t)(m0 + it*16 + srow) * lda + k0 + sf4);
  };
  auto ldW = [&](int k0) {
#pragma unroll
    for (int it = 0; it < 8; it++) {
      int r = n0 + it*16 + srow;
      pw[it] = (r < N) ? *(const float4*)(W + (size_t)r * ldw + k0 + sf4)
                       : make_float4(0.f, 0.f, 0.f, 0.f);
    }
  };
  auto st = [&]() {
#pragma unroll
    for (int it = 0; it < 8; it++) {
      int r = it*16 + srow;
      uint2 u1; u1.x = pack2(pa[it].x, pa[it].y); u1.y = pack2(pa[it].z, pa[it].w);
      *(uint2*)&As[r * GSTR + sf4] = u1;
      uint2 u2; u2.x = pack2(pw[it].x, pw[it].y); u2.y = pack2(pw[it].z, pw[it].w);
      *(uint2*)&Ws2[r * GSTR + sf4] = u2;
    }
  };

  f32x4_t acc[4][4];
#pragma unroll
  for (int i = 0; i < 4; i++)
#pragma unroll
    for (int j = 0; j < 4; j++) acc[i][j] = (f32x4_t){0.f, 0.f, 0.f, 0.f};

  ldA(0); ldW(0); st();
  __syncthreads();
  for (int k0 = 0; ; ) {
    int kn = k0 + 64;
    if (kn < K) { ldA(kn); ldW(kn); }
#pragma unroll
    for (int kk = 0; kk < 2; kk++) {
      bf16x8_t af[4], wf[4];
#pragma unroll
      for (int i = 0; i < 4; i++)
        af[i] = *(const bf16x8_t*)&As[(mw + 16*i + lr) * GSTR + kk*32 + lg*8];
#pragma unroll
      for (int j = 0; j < 4; j++)
        wf[j] = *(const bf16x8_t*)&Ws2[(nw + 16*j + lr) * GSTR + kk*32 + lg*8];
#pragma unroll
      for (int i = 0; i < 4; i++)
#pragma unroll
        for (int j = 0; j < 4; j++)
          acc[i][j] = __builtin_amdgcn_mfma_f32_16x16x32_bf16(af[i], wf[j], acc[i][j], 0, 0, 0);
    }
    k0 = kn;
    if (k0 >= K) break;
    __syncthreads();
    st();
    __syncthreads();
  }
  // epilogue: D row=(lane>>4)*4+reg (m), col=lane&15 (n)
#pragma unroll
  for (int j = 0; j < 4; j++) {
    int n = n0 + nw + 16*j + lr;
    if (n < N) {
      float bv = bias[n];
#pragma unroll
      for (int i = 0; i < 4; i++) {
#pragma unroll
        for (int r = 0; r < 4; r++) {
          int m = m0 + mw + 16*i + 4*lg + r;
          size_t off = (size_t)m * ldc + n;
          float v = acc[i][j][r] + bv;
          if (RESID) v += resid[off];
          C[off] = v;
          if (C2F) C2[off] = v;
        }
      }
    }
  }
}

// ===================== RoPE =====================
__global__ __launch_bounds__(256) void rope_q_kernel(float* qbuf)
{
  int id = blockIdx.x * 256 + threadIdx.x;     // NTOK*NH*16
  int d = id & 15;
  int h = (id >> 4) & 15;
  int sr = id >> 8;
  int s = sr & (NS - 1);
  float inv = __expf(-(float)(2 * d) * (9.210340371976184f / 32.f)); // 10000^(-2d/32)
  float fr = (float)s * inv;
  float sn, cs; sincosf(fr, &sn, &cs);
  float* p = qbuf + (size_t)sr * 1536 + h * 96 + 64;
  float x1 = p[d], x2 = p[d + 16];
  p[d]      = x1 * cs - x2 * sn;
  p[d + 16] = x2 * cs + x1 * sn;
}

__global__ __launch_bounds__(256) void rope_k_kernel(float* kvp)
{
  int id = blockIdx.x * 256 + threadIdx.x;     // NTOK*16
  int d = id & 15;
  int sr = id >> 4;
  int s = sr & (NS - 1);
  float inv = __expf(-(float)(2 * d) * (9.210340371976184f / 32.f));
  float fr = (float)s * inv;
  float sn, cs; sincosf(fr, &sn, &cs);
  float* p = kvp + (size_t)sr * 288 + 256;
  float x1 = p[d], x2 = p[d + 16];
  p[d]      = x1 * cs - x2 * sn;
  p[d + 16] = x2 * cs + x1 * sn;
}

// ===================== MLA flash attention (bf16 MFMA) — unchanged from R2 =====================
#define QPAD 296
#define VPAD 40
#define OSTR 260

__global__ __launch_bounds__(256) void attn_kernel(
    const float* __restrict__ qbuf,  // (NTOK, H*96)
    const float* __restrict__ kvn,   // (NTOK, 256)
    const float* __restrict__ kvp,   // (NTOK, 288), pe at +256
    const float* __restrict__ wkvb,  // (H*128, 256)
    float* __restrict__ oproj)       // (NTOK, H*64)
{
  extern __shared__ float4 smem_f4[];
  short* qs = (short*)smem_f4;
  short* ks = qs + 64 * QPAD;
  short* vt = qs + 96 * QPAD;
  short* ps = vt + 256 * VPAD;
  float* o_lds = (float*)smem_f4;
  float* qn = (float*)ks;

  int qb = (NS / 64 - 1) - blockIdx.x;
  int h = blockIdx.y, b = blockIdx.z;
  int t = threadIdx.x;
  int row0 = b * NS + qb * 64;
  const float scale = 0.10206207261596577f;  // 1/sqrt(96)

  for (int idx = t; idx < 64 * 96; idx += 256) {
    int r = idx / 96, c = idx % 96;
    float v = qbuf[(size_t)(row0 + r) * 1536 + h * 96 + c] * scale;
    if (c < 64) qn[r * 68 + c] = v;
    else        qs[r * QPAD + 256 + (c - 64)] = f2bfs(v);
  }
  __syncthreads();
  {
    int cx = t & 63, ry = t >> 6;
    float a[16][4] = {};
    const float* wb = wkvb + (size_t)h * 128 * 256 + cx * 4;
    for (int k = 0; k < 64; k++) {
      float4 wv = *(const float4*)(wb + (size_t)k * 256);
#pragma unroll
      for (int r = 0; r < 16; r++) {
        float qv = qn[(ry * 16 + r) * 68 + k];
        a[r][0] += qv * wv.x; a[r][1] += qv * wv.y; a[r][2] += qv * wv.z; a[r][3] += qv * wv.w;
      }
    }
    __syncthreads();
#pragma unroll
    for (int r = 0; r < 16; r++) {
      uint2 pk; pk.x = pack2(a[r][0], a[r][1]); pk.y = pack2(a[r][2], a[r][3]);
      *(uint2*)&qs[(ry * 16 + r) * QPAD + cx * 4] = pk;
    }
  }
  __syncthreads();

  int lane = t & 63, wv_ = t >> 6;
  int lrow = lane & 15, lg = lane >> 4;
  float m_run = -1e30f, l_run = 0.f;
  f32x4_t acco[16];
#pragma unroll
  for (int n = 0; n < 16; n++) acco[n] = (f32x4_t){0.f, 0.f, 0.f, 0.f};

  int nkb = 2 * qb + 2;
  for (int kb = 0; kb < nkb; kb++) {
    int key0 = kb * 32;
    size_t tb = (size_t)b * NS + key0;
#pragma unroll
    for (int it = 0; it < 8; it++) {
      int idx = it * 256 + t;
      int key = idx >> 6, f4 = (idx & 63) << 2;
      float4 v = *(const float4*)(kvn + (tb + key) * 256 + f4);
      uint2 pk; pk.x = pack2(v.x, v.y); pk.y = pack2(v.z, v.w);
      *(uint2*)&ks[key * QPAD + f4] = pk;
    }
    {
      int key = t >> 3, c4 = (t & 7) << 2;
      float4 v = *(const float4*)(kvp + (tb + key) * 288 + 256 + c4);
      uint2 pk; pk.x = pack2(v.x, v.y); pk.y = pack2(v.z, v.w);
      *(uint2*)&ks[key * QPAD + 256 + c4] = pk;
    }
#pragma unroll
    for (int it = 0; it < 8; it++) {
      int idx = it * 256 + t;
      int feat = idx & 255, k4 = (idx >> 8) << 2;
      const float* s0 = kvn + (tb + k4) * 256 + feat;
      float a0 = s0[0], a1 = s0[256], a2 = s0[512], a3 = s0[768];
      uint2 pk; pk.x = pack2(a0, a1); pk.y = pack2(a2, a3);
      *(uint2*)&vt[feat * VPAD + k4] = pk;
    }
    __syncthreads();
    f32x4_t s0a = {0.f, 0.f, 0.f, 0.f}, s1a = {0.f, 0.f, 0.f, 0.f};
#pragma unroll
    for (int kk = 0; kk < 9; kk++) {
      bf16x8_t bq = *(const bf16x8_t*)&qs[(16 * wv_ + lrow) * QPAD + kk * 32 + lg * 8];
      bf16x8_t a0 = *(const bf16x8_t*)&ks[lrow * QPAD + kk * 32 + lg * 8];
      bf16x8_t a1 = *(const bf16x8_t*)&ks[(16 + lrow) * QPAD + kk * 32 + lg * 8];
      s0a = __builtin_amdgcn_mfma_f32_16x16x32_bf16(a0, bq, s0a, 0, 0, 0);
      s1a = __builtin_amdgcn_mfma_f32_16x16x32_bf16(a1, bq, s1a, 0, 0, 0);
    }
    int qg = qb * 64 + 16 * wv_ + lrow;
    float sv[8];
#pragma unroll
    for (int r = 0; r < 4; r++) {
      sv[r]     = (key0 + 4 * lg + r      <= qg) ? s0a[r] : -1e30f;
      sv[4 + r] = (key0 + 16 + 4 * lg + r <= qg) ? s1a[r] : -1e30f;
    }
    float mx = sv[0];
#pragma unroll
    for (int i = 1; i < 8; i++) mx = fmaxf(mx, sv[i]);
    mx = fmaxf(mx, __shfl_xor(mx, 16));
    mx = fmaxf(mx, __shfl_xor(mx, 32));
    float mnew = fmaxf(m_run, mx);
    float al = __expf(m_run - mnew);
    float sum = 0.f;
#pragma unroll
    for (int i = 0; i < 8; i++) { sv[i] = __expf(sv[i] - mnew); sum += sv[i]; }
    sum += __shfl_xor(sum, 16);
    sum += __shfl_xor(sum, 32);
    l_run = l_run * al + sum;
    m_run = mnew;
    {
      int q = 16 * wv_ + lrow, swz = q & 3;
      int g0 = lg >> 1, h0 = lg & 1;
      uint2 p0; p0.x = pack2(sv[0], sv[1]); p0.y = pack2(sv[2], sv[3]);
      uint2 p1; p1.x = pack2(sv[4], sv[5]); p1.y = pack2(sv[6], sv[7]);
      char* pr = (char*)ps + q * 64;
      *(uint2*)(pr + ((g0 ^ swz) * 16 + h0 * 8))       = p0;
      *(uint2*)(pr + (((2 + g0) ^ swz) * 16 + h0 * 8)) = p1;
    }
    {
      float al0 = __shfl(al, 4 * lg + 0);
      float al1 = __shfl(al, 4 * lg + 1);
      float al2 = __shfl(al, 4 * lg + 2);
      float al3 = __shfl(al, 4 * lg + 3);
#pragma unroll
      for (int n = 0; n < 16; n++) {
        acco[n][0] *= al0; acco[n][1] *= al1; acco[n][2] *= al2; acco[n][3] *= al3;
      }
    }
    {
      int q = 16 * wv_ + lrow;
      bf16x8_t ap = *(const bf16x8_t*)((char*)ps + q * 64 + ((lg ^ (q & 3)) * 16));
#pragma unroll
      for (int n = 0; n < 16; n++) {
        bf16x8_t bv = *(const bf16x8_t*)&vt[(n * 16 + lrow) * VPAD + lg * 8];
        acco[n] = __builtin_amdgcn_mfma_f32_16x16x32_bf16(ap, bv, acco[n], 0, 0, 0);
      }
    }
    __syncthreads();
  }
  {
    float li = 1.f / l_run;
    float l0 = __shfl(li, 4 * lg + 0);
    float l1 = __shfl(li, 4 * lg + 1);
    float l2 = __shfl(li, 4 * lg + 2);
    float l3 = __shfl(li, 4 * lg + 3);
#pragma unroll
    for (int n = 0; n < 16; n++) {
      int fc = n * 16 + lrow;
      o_lds[(16 * wv_ + 4 * lg + 0) * OSTR + fc] = acco[n][0] * l0;
      o_lds[(16 * wv_ + 4 * lg + 1) * OSTR + fc] = acco[n][1] * l1;
      o_lds[(16 * wv_ + 4 * lg + 2) * OSTR + fc] = acco[n][2] * l2;
      o_lds[(16 * wv_ + 4 * lg + 3) * OSTR + fc] = acco[n][3] * l3;
    }
  }
  __syncthreads();
  {
    int dx = t & 15, ty2 = t >> 4;
    float pr[4][4] = {};
    const float* wb = wkvb + (size_t)(h * 128 + 64) * 256;
    for (int c = 0; c < 256; c += 4) {
      float4 w0 = *(const float4*)(wb + (size_t)(dx * 4 + 0) * 256 + c);
      float4 w1 = *(const float4*)(wb + (size_t)(dx * 4 + 1) * 256 + c);
      float4 w2 = *(const float4*)(wb + (size_t)(dx * 4 + 2) * 256 + c);
      float4 w3 = *(const float4*)(wb + (size_t)(dx * 4 + 3) * 256 + c);
#pragma unroll
      for (int i = 0; i < 4; i++) {
        float4 ov = *(const float4*)&o_lds[(ty2 * 4 + i) * OSTR + c];
        pr[i][0] += ov.x*w0.x + ov.y*w0.y + ov.z*w0.z + ov.w*w0.w;
        pr[i][1] += ov.x*w1.x + ov.y*w1.y + ov.z*w1.z + ov.w*w1.w;
        pr[i][2] += ov.x*w2.x + ov.y*w2.y + ov.z*w2.z + ov.w*w2.w;
        pr[i][3] += ov.x*w3.x + ov.y*w3.y + ov.z*w3.z + ov.w*w3.w;
      }
    }
#pragma unroll
    for (int i = 0; i < 4; i++)
#pragma unroll
      for (int j = 0; j < 4; j++)
        oproj[(size_t)(row0 + ty2 * 4 + i) * 1024 + h * 64 + dx * 4 + j] = pr[i][j];
  }
}

// ===================== gate logits =====================
__global__ __launch_bounds__(256) void gate_kernel(
    const float* __restrict__ Y, const float* __restrict__ gw,
    const float* __restrict__ gb, float* __restrict__ logits)
{
  __shared__ __align__(16) float ly[1024];
  int tok = blockIdx.x, t = threadIdx.x;
  *(float4*)&ly[t * 4] = *(const float4*)(Y + (size_t)tok * ND + t * 4);
  __syncthreads();
  int e = t >> 5, lane = t & 31;
  const float* w = gw + (size_t)e * ND;
  float ss = 0.f;
  for (int d = lane; d < ND; d += 32) ss += ly[d] * w[d];
#pragma unroll
  for (int k = 16; k >= 1; k >>= 1) ss += __shfl_xor(ss, k);
  if (lane == 0) logits[(size_t)tok * 8 + e] = ss + gb[e];
}

// ===================== top-2 gating + counts =====================
__global__ __launch_bounds__(256) void topk_kernel(
    const float* __restrict__ logits, int* __restrict__ tke,
    float* __restrict__ tkw, int* __restrict__ cnt)
{
  int tok = blockIdx.x * 256 + threadIdx.x;
  if (tok >= NTOK) return;
  float l[8];
#pragma unroll
  for (int e2 = 0; e2 < 8; e2++) l[e2] = logits[(size_t)tok * 8 + e2];
  float v0 = l[0]; int e0 = 0;
#pragma unroll
  for (int e2 = 1; e2 < 8; e2++) if (l[e2] > v0) { v0 = l[e2]; e0 = e2; }
  float v1 = -INFINITY; int e1 = 0;
#pragma unroll
  for (int e2 = 0; e2 < 8; e2++) if (e2 != e0 && l[e2] > v1) { v1 = l[e2]; e1 = e2; }
  float x = __expf(v1 - v0);
  float w0 = 1.f / (1.f + x);
  tke[tok * 2]     = e0; tke[tok * 2 + 1] = e1;
  tkw[tok * 2]     = w0; tkw[tok * 2 + 1] = 1.f - w0;
  atomicAdd(&cnt[e0], 1);
  atomicAdd(&cnt[8 + e1], 1);
}

__global__ void offsets_kernel(const int* cnt, int* base, int* pcnt)
{
  if (threadIdx.x == 0 && blockIdx.x == 0) {
    int cum = 0;
    for (int s2 = 0; s2 < 16; s2++) {
      int p = (cnt[s2] + 127) & ~127;   // pad to 128 (MFMA tile height)
      base[s2] = cum; pcnt[s2] = p; cum += p;
    }
  }
}

__global__ __launch_bounds__(256) void scatter_kernel(
    const int* __restrict__ tke, const float* __restrict__ tkw,
    const int* __restrict__ base, int* cnt2,
    int* __restrict__ etok, float* __restrict__ ew)
{
  int tok = blockIdx.x * 256 + threadIdx.x;
  if (tok >= NTOK) return;
#pragma unroll
  for (int k = 0; k < 2; k++) {
    int e = tke[tok * 2 + k];
    int seg = k * 8 + e;
    int pos = atomicAdd(&cnt2[seg], 1);
    int row = base[seg] + pos;
    etok[row] = tok;
    ew[row] = tkw[tok * 2 + k];
  }
}

// ===================== MoE mlp1 (MFMA): act = silu(y@gp^T) * (y@up^T), gathered =====================
// 128x128 tile, BK=32, 3 staged matrices, 2 accumulator sets.
#define MSTR 40   // shorts per LDS row (32 data + 8 pad); 80B: 16B-aligned, 2-way banks

__global__ __launch_bounds__(256) void moe_mlp1_mfma(
    const float* __restrict__ Y,
    const float* __restrict__ Gp, const float* __restrict__ Up,
    const int* __restrict__ etok, const int* __restrict__ base,
    const int* __restrict__ pcnt, float* __restrict__ act)
{
  int seg = blockIdx.z;
  if ((int)(blockIdx.y * 128) >= pcnt[seg]) return;
  int e = seg & 7;
  __shared__ __align__(16) short As[128 * MSTR];
  __shared__ __align__(16) short Gs[128 * MSTR];
  __shared__ __align__(16) short Us[128 * MSTR];
  int t = threadIdx.x;
  int row0 = base[seg] + blockIdx.y * 128;
  int n0 = blockIdx.x * 128;
  int srow = t >> 3, sf4 = (t & 7) * 4;      // staging: row srow(+32it), float-col sf4
  int lane = t & 63, w = t >> 6;
  int mw = (w >> 1) * 64, nw = (w & 1) * 64;
  int lr = lane & 15, lg = lane >> 4;

  int tokr[4];
#pragma unroll
  for (int it = 0; it < 4; it++) tokr[it] = etok[row0 + it*32 + srow];

  float4 pa[4], pg[4], pu[4];
  auto ld = [&](int k0) {
#pragma unroll
    for (int it = 0; it < 4; it++) {
      int r = it*32 + srow;
      pa[it] = (tokr[it] >= 0)
        ? *(const float4*)(Y + (size_t)tokr[it] * ND + k0 + sf4)
        : make_float4(0.f, 0.f, 0.f, 0.f);
      pg[it] = *(const float4*)(Gp + ((size_t)e * NFE + n0 + r) * ND + k0 + sf4);
      pu[it] = *(const float4*)(Up + ((size_t)e * NFE + n0 + r) * ND + k0 + sf4);
    }
  };
  auto st = [&]() {
#pragma unroll
    for (int it = 0; it < 4; it++) {
      int r = it*32 + srow;
      uint2 u1; u1.x = pack2(pa[it].x, pa[it].y); u1.y = pack2(pa[it].z, pa[it].w);
      *(uint2*)&As[r * MSTR + sf4] = u1;
      uint2 u2; u2.x = pack2(pg[it].x, pg[it].y); u2.y = pack2(pg[it].z, pg[it].w);
      *(uint2*)&Gs[r * MSTR + sf4] = u2;
      uint2 u3; u3.x = pack2(pu[it].x, pu[it].y); u3.y = pack2(pu[it].z, pu[it].w);
      *(uint2*)&Us[r * MSTR + sf4] = u3;
    }
  };

  f32x4_t accg[4][4], accu[4][4];
#pragma unroll
  for (int i = 0; i < 4; i++)
#pragma unroll
    for (int j = 0; j < 4; j++) {
      accg[i][j] = (f32x4_t){0.f, 0.f, 0.f, 0.f};
      accu[i][j] = (f32x4_t){0.f, 0.f, 0.f, 0.f};
    }

  ld(0); st();
  __syncthreads();
  for (int k0 = 0; ; ) {
    int kn = k0 + 32;
    if (kn < ND) ld(kn);
    bf16x8_t af[4], gf[4], uf[4];
#pragma unroll
    for (int i = 0; i < 4; i++)
      af[i] = *(const bf16x8_t*)&As[(mw + 16*i + lr) * MSTR + lg*8];
#pragma unroll
    for (int j = 0; j < 4; j++) {
      gf[j] = *(const bf16x8_t*)&Gs[(nw + 16*j + lr) * MSTR + lg*8];
      uf[j] = *(const bf16x8_t*)&Us[(nw + 16*j + lr) * MSTR + lg*8];
    }
#pragma unroll
    for (int i = 0; i < 4; i++)
#pragma unroll
      for (int j = 0; j < 4; j++) {
        accg[i][j] = __builtin_amdgcn_mfma_f32_16x16x32_bf16(af[i], gf[j], accg[i][j], 0, 0, 0);
        accu[i][j] = __builtin_amdgcn_mfma_f32_16x16x32_bf16(af[i], uf[j], accu[i][j], 0, 0, 0);
      }
    k0 = kn;
    if (k0 >= ND) break;
    __syncthreads();
    st();
    __syncthreads();
  }
#pragma unroll
  for (int i = 0; i < 4; i++)
#pragma unroll
    for (int j = 0; j < 4; j++) {
      int n = n0 + nw + 16*j + lr;
#pragma unroll
      for (int r = 0; r < 4; r++) {
        int m = row0 + mw + 16*i + 4*lg + r;
        float g = accg[i][j][r], u = accu[i][j][r];
        float s = g / (1.f + __expf(-g));
        act[(size_t)m * NFE + n] = s * u;
      }
    }
}

// ===================== MoE down (MFMA): out[tok] += w * (act @ dp^T) =====================
__global__ __launch_bounds__(256) void moe_down_mfma(
    const float* __restrict__ act, const float* __restrict__ Dp,
    const int* __restrict__ etok, const float* __restrict__ ew,
    const int* __restrict__ base, const int* __restrict__ pcnt,
    int slot, float* __restrict__ out)
{
  int e = blockIdx.z;
  int seg = slot * 8 + e;
  if ((int)(blockIdx.y * 128) >= pcnt[seg]) return;
  __shared__ __align__(16) short As[128 * GSTR];
  __shared__ __align__(16) short Ws2[128 * GSTR];
  int t = threadIdx.x;
  int row0 = base[seg] + blockIdx.y * 128;
  int n0 = blockIdx.x * 128;
  int srow = t >> 4, sf4 = (t & 15) * 4;
  int lane = t & 63, w = t >> 6;
  int mw = (w >> 1) * 64, nw = (w & 1) * 64;
  int lr = lane & 15, lg = lane >> 4;

  float4 pa[8], pw[8];
  auto ld = [&](int k0) {
#pragma unroll
    for (int it = 0; it < 8; it++) {
      int r = it*16 + srow;
      pa[it] = *(const float4*)(act + (size_t)(row0 + r) * NFE + k0 + sf4);
      pw[it] = *(const float4*)(Dp + ((size_t)e * ND + n0 + r) * NFE + k0 + sf4);
    }
  };
  auto st = [&]() {
#pragma unroll
    for (int it = 0; it < 8; it++) {
      int r = it*16 + srow;
      uint2 u1; u1.x = pack2(pa[it].x, pa[it].y); u1.y = pack2(pa[it].z, pa[it].w);
      *(uint2*)&As[r * GSTR + sf4] = u1;
      uint2 u2; u2.x = pack2(pw[it].x, pw[it].y); u2.y = pack2(pw[it].z, pw[it].w);
      *(uint2*)&Ws2[r * GSTR + sf4] = u2;
    }
  };

  f32x4_t acc[4][4];
#pragma unroll
  for (int i = 0; i < 4; i++)
#pragma unroll
    for (int j = 0; j < 4; j++) acc[i][j] = (f32x4_t){0.f, 0.f, 0.f, 0.f};

  ld(0); st();
  __syncthreads();
  for (int k0 = 0; ; ) {
    int kn = k0 + 64;
    if (kn < NFE) ld(kn);
#pragma unroll
    for (int kk = 0; kk < 2; kk++) {
      bf16x8_t af[4], wf[4];
#pragma unroll
      for (int i = 0; i < 4; i++)
        af[i] = *(const bf16x8_t*)&As[(mw + 16*i + lr) * GSTR + kk*32 + lg*8];
#pragma unroll
      for (int j = 0; j < 4; j++)
        wf[j] = *(const bf16x8_t*)&Ws2[(nw + 16*j + lr) * GSTR + kk*32 + lg*8];
#pragma unroll
      for (int i = 0; i < 4; i++)
#pragma unroll
        for (int j = 0; j < 4; j++)
          acc[i][j] = __builtin_amdgcn_mfma_f32_16x16x32_bf16(af[i], wf[j], acc[i][j], 0, 0, 0);
    }
    k0 = kn;
    if (k0 >= NFE) break;
    __syncthreads();
    st();
    __syncthreads();
  }
#pragma unroll
  for (int i = 0; i < 4; i++) {
    int tks[4]; float ews[4];
#pragma unroll
    for (int r = 0; r < 4; r++) {
      int rg = row0 + mw + 16*i + 4*lg + r;
      tks[r] = etok[rg]; ews[r] = ew[rg];
    }
#pragma unroll
    for (int j = 0; j < 4; j++) {
      int n = n0 + nw + 16*j + lr;
#pragma unroll
      for (int r = 0; r < 4; r++) {
        if (tks[r] >= 0)
          out[(size_t)tks[r] * ND + n] += ews[r] * acc[i][j][r];
      }
    }
  }
}

// ===================== launch =====================
extern "C" void kernel_launch(void* const* d_in, const int* in_sizes, int n_in,
                              void* d_out, int out_size, void* d_ws, size_t ws_size,
                              hipStream_t stream) {
  const float* hidden    = (const float*)d_in[0];
  const float* in_ln_w   = (const float*)d_in[2];
  const float* post_ln_w = (const float*)d_in[3];
  const float* wq_a_w    = (const float*)d_in[4];
  const float* wq_a_b    = (const float*)d_in[5];
  const float* q_norm_w  = (const float*)d_in[6];
  const float* wq_b_w    = (const float*)d_in[7];
  const float* wq_b_b    = (const float*)d_in[8];
  const float* wkv_a_w   = (const float*)d_in[9];
  const float* wkv_a_b   = (const float*)d_in[10];
  const float* kv_norm_w = (const float*)d_in[11];
  const float* wkv_b_w   = (const float*)d_in[12];
  const float* wo_w      = (const float*)d_in[13];
  const float* wo_b      = (const float*)d_in[14];
  const float* gate_w    = (const float*)d_in[15];
  const float* gate_b    = (const float*)d_in[16];
  const float* gate_proj = (const float*)d_in[17];
  const float* up_proj   = (const float*)d_in[18];
  const float* down_proj = (const float*)d_in[19];

  float* ws = (float*)d_ws;
  if (ws_size < WS_FLOATS * sizeof(float)) return;

  float* x     = ws + OFF_X;
  float* qa    = ws + OFF_QA;
  float* qbuf  = ws + OFF_QB;
  float* kvp   = ws + OFF_KVP;
  float* kvn   = ws + OFF_KVN;
  float* hbuf  = ws + OFF_H;
  float* ybuf  = ws + OFF_Y;
  float* tkw   = ws + OFF_TKW;
  float* ew    = ws + OFF_EW;
  float* actb  = ws + OFF_ACT;
  float* oproj = ws + OFF_OPROJ;
  int* ib   = (int*)(ws + OFF_INT);
  int* tke  = ib + IOFF_TKE;
  int* etok = ib + IOFF_ETOK;
  int* cnt  = ib + IOFF_CNT;
  int* cnt2 = cnt + 16;
  int* base = cnt + 32;
  int* pcnt = cnt + 48;

  float* out    = (float*)d_out;
  float* logits = out + (size_t)NTOK * ND;

  rmsnorm_kernel<4><<<NTOK, 256, 0, stream>>>(hidden, ND, in_ln_w, x, ND);
  // q_pre = x @ wq_a^T + b   (N=512, K=1024)
  gemm_bf16<false,false><<<dim3(4, 32), 256, 0, stream>>>(
      x, ND, wq_a_w, ND, wq_a_b, nullptr, qa, 512, nullptr, 512, ND);
  // kvp = x @ wkv_a^T + b    (N=288, K=1024)
  gemm_bf16<false,false><<<dim3(3, 32), 256, 0, stream>>>(
      x, ND, wkv_a_w, ND, wkv_a_b, nullptr, kvp, 288, nullptr, 288, ND);
  rmsnorm_kernel<2><<<NTOK, 256, 0, stream>>>(qa, 512, q_norm_w, qa, 512);
  rmsnorm_kernel<1><<<NTOK, 256, 0, stream>>>(kvp, 288, kv_norm_w, kvn, 256);
  // qbuf = q @ wq_b^T + b    (N=1536, K=512)
  gemm_bf16<false,false><<<dim3(12, 32), 256, 0, stream>>>(
      qa, 512, wq_b_w, 512, wq_b_b, nullptr, qbuf, 1536, nullptr, 1536, 512);
  rope_q_kernel<<<4096, 256, 0, stream>>>(qbuf);
  rope_k_kernel<<<256, 256, 0, stream>>>(kvp);
  {
    size_t smem = (size_t)(64*QPAD + 32*QPAD + 256*VPAD + 64*32) * sizeof(short); // 81408
    hipFuncSetAttribute((const void*)attn_kernel,
                        hipFuncAttributeMaxDynamicSharedMemorySize, (int)smem);
    attn_kernel<<<dim3(NS / 64, NH, NB), 256, smem, stream>>>(qbuf, kvn, kvp, wkv_b_w, oproj);
  }
  // h = oproj @ wo^T + wo_b + hidden ; also seed out with h   (N=1024, K=1024)
  gemm_bf16<true,true><<<dim3(8, 32), 256, 0, stream>>>(
      oproj, ND, wo_w, ND, wo_b, hidden, hbuf, ND, out, ND, ND);
  rmsnorm_kernel<4><<<NTOK, 256, 0, stream>>>(hbuf, ND, post_ln_w, ybuf, ND);
  gate_kernel<<<NTOK, 256, 0, stream>>>(ybuf, gate_w, gate_b, logits);
  hipMemsetAsync(cnt, 0, 32 * sizeof(int), stream);
  hipMemsetAsync(etok, 0xFF, ETOK_CAP * sizeof(int), stream);
  topk_kernel<<<16, 256, 0, stream>>>(logits, tke, tkw, cnt);
  offsets_kernel<<<1, 64, 0, stream>>>(cnt, base, pcnt);
  scatter_kernel<<<16, 256, 0, stream>>>(tke, tkw, base, cnt2, etok, ew);
  moe_mlp1_mfma<<<dim3(8, 32, 16), 256, 0, stream>>>(ybuf, gate_proj, up_proj,
                                                     etok, base, pcnt, actb);
  moe_down_mfma<<<dim3(8, 32, 8), 256, 0, stream>>>(actb, down_proj, etok, ew,
                                                    base, pcnt, 0, out);
  moe_down_mfma<<<dim3(8, 32, 8), 256, 0, stream>>>(actb, down_proj, etok, ew,
                                                    base, pcnt, 1, out);
}